// Round 4
// baseline (217.614 us; speedup 1.0000x reference)
//
#include <hip/hip_runtime.h>
#include <hip/hip_bf16.h>
#include <stdint.h>

// Problem constants (B=16, C=256, NH=4, D=64, G=32, L=HW=1024)
// Round 20. R19 post-mortem: conflicts -5.3x, FETCH -6x (XCD swizzle) but
// attn FLAT at 74.5us -> serial critical path per chunk is the bottleneck
// (shfl chains + LDS bounce w/ lgkmcnt fence blocking cross-chunk overlap).
// This round: attn main loop restructured to mfma_f32_32x32x16_bf16.
//  - Lane owns ONE q (C/D col=lane&31): cmax/psum = in-lane tree + 1
//    shfl_xor(32); alpha/m/l lane-local scalars (8 al-shfls removed).
//  - PV as O^T = V^T*P: P B-frag built in-register via 8 bf16-packs +
//    4 permlane32_swap (T12) - LDS bounce + asm fences DELETED. Main loop
//    is pure register dataflow; compiler free to overlap chunks.
//  - 8 MFMAs/chunk (4 S + 4 PV) vs 16. K prefetch double-buffer kept.
//  - Combine epilogue unchanged (f32 Ow in LDS, 1 barrier).
// Other kernels unchanged from R19 (green, absmax 0.03125).

typedef __hip_bfloat16 bf16;
typedef __attribute__((ext_vector_type(8))) short short8;
typedef __attribute__((ext_vector_type(4))) float float4v;
typedef __attribute__((ext_vector_type(16))) float float16v;

__global__ __launch_bounds__(256) void stats_kernel(const float* __restrict__ x,
    float2* __restrict__ stats) {
  int b = blockIdx.x >> 5, g = blockIdx.x & 31;
  const float* xp = x + (size_t)(b * 256 + g * 8) * 1024;
  float s = 0.f, ss = 0.f;
  for (int i = threadIdx.x; i < 8192; i += 256) {
    float v = xp[i]; s += v; ss += v * v;
  }
  #pragma unroll
  for (int o = 32; o; o >>= 1) { s += __shfl_down(s, o); ss += __shfl_down(ss, o); }
  __shared__ float red[2][4];
  int wid = threadIdx.x >> 6;
  if ((threadIdx.x & 63) == 0) { red[0][wid] = s; red[1][wid] = ss; }
  __syncthreads();
  if (threadIdx.x == 0) {
    s  = red[0][0] + red[0][1] + red[0][2] + red[0][3];
    ss = red[1][0] + red[1][1] + red[1][2] + red[1][3];
    float mean = s * (1.f / 8192.f);
    float var  = ss * (1.f / 8192.f) - mean * mean;
    stats[blockIdx.x] = make_float2(mean, rsqrtf(var + 1e-5f));
  }
}

// GN + transpose: hT[zb][l][c] = GN(x)[b][c][l], bf16.
__global__ __launch_bounds__(256) void gnt_kernel(const float* __restrict__ x,
    const float* __restrict__ gamma, const float* __restrict__ beta,
    const float2* __restrict__ stats, bf16* __restrict__ hT, int b_off) {
  __shared__ float T[64][65];
  int zb = blockIdx.z, b = zb + b_off;
  int c0 = blockIdx.y * 64, l0 = blockIdx.x * 64;
  const float* xb = x + (size_t)b * 262144;
  const float2* st = stats + b * 32;
  int tid = threadIdx.x;
  for (int i = tid; i < 4096; i += 256) {
    int cl = i >> 6, ll = i & 63;
    int c = c0 + cl;
    float2 s2 = st[c >> 3];
    T[cl][ll] = (xb[(size_t)c * 1024 + l0 + ll] - s2.x) * s2.y * gamma[c] + beta[c];
  }
  __syncthreads();
  bf16* hb = hT + (size_t)zb * 262144;
  for (int i = tid; i < 4096; i += 256) {
    int ll = i >> 6, cl = i & 63;
    hb[(size_t)(l0 + ll) * 256 + c0 + cl] = __float2bfloat16(T[cl][ll]);
  }
}

__global__ __launch_bounds__(256) void wpack(const float* __restrict__ wq,
    const float* __restrict__ wk, const float* __restrict__ wv,
    const float* __restrict__ wp, bf16* __restrict__ Wb, bf16* __restrict__ Pb) {
  int i = blockIdx.x * 256 + threadIdx.x;        // 262144 total
  if (i < 196608) {
    int r = i >> 8, c = i & 255;
    const float* src = (r < 256) ? wq : (r < 512) ? wk : wv;
    Wb[i] = __float2bfloat16(src[(r & 255) * 256 + c]);
  } else {
    int j = i - 196608;
    Pb[j] = __float2bfloat16(wp[j]);
  }
}

// qkv GEMM on MFMA: C[m][l] = Wb[m][:]·h[:][l] + bias. B^T = hT rows.
// Q (sec 0) and K (sec 1) both written transposed per head: [l][64].
// Q pre-scaled by 1/8 (attention score scale, exact pow2).
__global__ __launch_bounds__(256) void gemm_qkv_mfma(
    const bf16* __restrict__ hT, const bf16* __restrict__ Wb,
    const float* __restrict__ bq, const float* __restrict__ bk,
    const float* __restrict__ bv,
    bf16* __restrict__ qkv, size_t qkv_bstride) {
  __shared__ bf16 As[128][40];
  __shared__ bf16 Bs[128][40];
  int zb = blockIdx.z;
  int m0 = blockIdx.y * 128, l0 = blockIdx.x * 128;
  const bf16* hb = hT + (size_t)zb * 262144;
  int tid = threadIdx.x, lane = tid & 63, wave = tid >> 6;
  int l16 = lane & 15, quad = lane >> 4;
  int mi0 = (wave & 1) * 4, nj0 = (wave >> 1) * 4;
  float4v acc[4][4];
  #pragma unroll
  for (int i = 0; i < 4; i++)
    #pragma unroll
    for (int j = 0; j < 4; j++) acc[i][j] = (float4v){0.f, 0.f, 0.f, 0.f};

  for (int kc = 0; kc < 8; kc++) {
    __syncthreads();
    #pragma unroll
    for (int it = 0; it < 2; it++) {
      int s = it * 256 + tid;
      int mm = s >> 2, kk = (s & 3) * 8;
      *(short8*)&As[mm][kk] = *(const short8*)&Wb[(size_t)(m0 + mm) * 256 + kc * 32 + kk];
      *(short8*)&Bs[mm][kk] = *(const short8*)&hb[(size_t)(l0 + mm) * 256 + kc * 32 + kk];
    }
    __syncthreads();
    short8 af[4], bfr[4];
    #pragma unroll
    for (int i = 0; i < 4; i++) af[i]  = *(const short8*)&As[(mi0 + i) * 16 + l16][quad * 8];
    #pragma unroll
    for (int j = 0; j < 4; j++) bfr[j] = *(const short8*)&Bs[(nj0 + j) * 16 + l16][quad * 8];
    #pragma unroll
    for (int i = 0; i < 4; i++)
      #pragma unroll
      for (int j = 0; j < 4; j++)
        acc[i][j] = __builtin_amdgcn_mfma_f32_16x16x32_bf16(af[i], bfr[j], acc[i][j], 0, 0, 0);
  }

  bf16* Cp = qkv + (size_t)zb * qkv_bstride;
  int sec = m0 >> 8;
  const float* bptr = (sec == 0) ? bq : (sec == 1) ? bk : bv;
  float osc = (sec == 0) ? 0.125f : 1.0f;
  #pragma unroll
  for (int i = 0; i < 4; i++) {
    #pragma unroll
    for (int r = 0; r < 4; r++) {
      int m = m0 + (mi0 + i) * 16 + quad * 4 + r;
      float bias = bptr[m & 255];
      if (sec <= 1) {
        int rr = m & 255;
        bf16* Tp = Cp + sec * 262144 + (rr >> 6) * 65536;   // per-head [l][64]
        #pragma unroll
        for (int j = 0; j < 4; j++) {
          int l = l0 + (nj0 + j) * 16 + l16;
          Tp[(size_t)l * 64 + (rr & 63)] = __float2bfloat16((acc[i][j][r] + bias) * osc);
        }
      } else {
        #pragma unroll
        for (int j = 0; j < 4; j++) {
          int l = l0 + (nj0 + j) * 16 + l16;
          Cp[(size_t)m * 1024 + l] = __float2bfloat16(acc[i][j][r] + bias);
        }
      }
    }
  }
}

// Flash MFMA attention, 32x32 MFMA + permlane P-redistribution.
// Block = (b, head, 32 q-rows); 4 waves each own a 32-key slice of every
// 128-key chunk. Lane owns one q column (C/D col = lane&31). No LDS and no
// barriers in the main loop.
__global__ __launch_bounds__(256) void attn_kernel(
    const bf16* __restrict__ qkv, bf16* __restrict__ oT,
    size_t qkv_bstride, size_t o_bstride) {
  __shared__ __align__(16) char lds_raw[34304];
  float* Ow = (float*)lds_raw;                   // combine: 4x32x65 f32 = 33280 B
  float* mS = (float*)(lds_raw + 33280);         // [4][32]
  float* lS = (float*)(lds_raw + 33792);         // [4][32]

  // Block id decode: full path (gridDim.z==16) uses an XCD swizzle so all
  // 32 q-blocks of head h land on wgid = h&7 (mod 8) -> one XCD's L2.
  int zb, n, q0;
  {
    int f = blockIdx.x + (blockIdx.y << 5) + (blockIdx.z << 7);
    if (gridDim.z == 16) {
      int c = f & 7, t2 = f >> 3;
      int h = ((t2 >> 5) << 3) + c;
      zb = h >> 2; n = h & 3; q0 = (t2 & 31) << 5;
    } else {
      zb = blockIdx.z; n = blockIdx.y; q0 = blockIdx.x << 5;
    }
  }
  const bf16* base = qkv + (size_t)zb * qkv_bstride;
  const bf16* QTp = base + (size_t)n * 65536;                       // [l][64], pre-scaled
  const bf16* KTp = base + (size_t)262144 + (size_t)n * 65536;      // [l][64]
  const bf16* Vp  = base + (size_t)524288 + (size_t)(n * 64) * 1024;
  int tid = threadIdx.x;
  int lane = tid & 63, wave = tid >> 6;
  int l31 = lane & 31, hb2 = lane >> 5;

  // Q B-frags: qb[ds] = Q^T[q0+l31][ds*16 + hb2*8 + j]  (col=q, k=d)
  short8 qb[4];
  #pragma unroll
  for (int ds = 0; ds < 4; ds++)
    qb[ds] = *(const short8*)&QTp[(size_t)(q0 + l31) * 64 + ds * 16 + hb2 * 8];

  float m_run = -1e30f, l_run = 0.f;
  float16v oaccT[2];
  #pragma unroll
  for (int dh = 0; dh < 2; dh++)
    #pragma unroll
    for (int r = 0; r < 16; r++) oaccT[dh][r] = 0.f;

  // half-swap: o0 = {a.lo-lanes, b.lo-lanes(moved hi)}, o1 = {a.hi-lanes(moved lo), b.hi-lanes}
  auto swp = [&](unsigned int a, unsigned int b, unsigned int& o0, unsigned int& o1) {
#if __has_builtin(__builtin_amdgcn_permlane32_swap)
    auto rr = __builtin_amdgcn_permlane32_swap((int)a, (int)b, false, false);
    o0 = (unsigned int)rr[0]; o1 = (unsigned int)rr[1];
#else
    unsigned int sa = (unsigned int)__shfl_xor((int)a, 32, 64);
    unsigned int sb = (unsigned int)__shfl_xor((int)b, 32, 64);
    o0 = hb2 ? sb : a;
    o1 = hb2 ? b : sa;
#endif
  };

  auto loadK = [&](short8 (&kf)[4], int mc) {
    const bf16* krow = KTp + (size_t)(mc * 128 + wave * 32 + l31) * 64 + hb2 * 8;
    #pragma unroll
    for (int ds = 0; ds < 4; ds++) kf[ds] = *(const short8*)&krow[ds * 16];
  };

  auto step = [&](short8 (&kf)[4], int mc) {
    int kbase = mc * 128 + wave * 32;
    // V^T A-frags: vf[dh][s] = V[dh*32+l31][kbase + s*16 + hb2*8 + j]
    short8 vf[2][2];
    #pragma unroll
    for (int dh = 0; dh < 2; dh++)
      #pragma unroll
      for (int s = 0; s < 2; s++)
        vf[dh][s] = *(const short8*)&Vp[(size_t)(dh * 32 + l31) * 1024 + kbase + s * 16 + hb2 * 8];

    // S[key 32][q 32] over d=64: 4 chained MFMAs
    float16v sacc;
    #pragma unroll
    for (int r = 0; r < 16; r++) sacc[r] = 0.f;
    #pragma unroll
    for (int ds = 0; ds < 4; ds++)
      sacc = __builtin_amdgcn_mfma_f32_32x32x16_bf16(kf[ds], qb[ds], sacc, 0, 0, 0);

    // online softmax: lane owns q=l31; 16 keys in-lane, 16 in lane^32
    float cmax = sacc[0];
    #pragma unroll
    for (int r = 1; r < 16; r++) cmax = fmaxf(cmax, sacc[r]);
    cmax = fmaxf(cmax, __shfl_xor(cmax, 32, 64));
    float mnew = fmaxf(m_run, cmax);
    int grew = __any(mnew > m_run);
    float alpha = __expf(m_run - mnew);
    float p[16];
    float psum = 0.f;
    #pragma unroll
    for (int r = 0; r < 16; r++) { p[r] = __expf(sacc[r] - mnew); psum += p[r]; }
    psum += __shfl_xor(psum, 32, 64);
    l_run = l_run * alpha + psum;
    m_run = mnew;

    // P -> PV B-frags in-register: pack pairs, permlane32_swap halves.
    // key(r) = (r&3) + 8*(r>>2) + 4*hb2; w[i] = keys (2i,2i+1) of that map.
    unsigned int w[8];
    #pragma unroll
    for (int i = 0; i < 8; i++) {
      bf16 plo = __float2bfloat16(p[2 * i]);
      bf16 phi = __float2bfloat16(p[2 * i + 1]);
      w[i] = (unsigned int)*(unsigned short*)&plo |
             ((unsigned int)*(unsigned short*)&phi << 16);
    }
    short8 pb[2];
    {
      unsigned int o0, o1, o2, o3;
      swp(w[0], w[2], o0, o2); swp(w[1], w[3], o1, o3);
      unsigned int* pw = (unsigned int*)&pb[0];
      pw[0] = o0; pw[1] = o1; pw[2] = o2; pw[3] = o3;
      swp(w[4], w[6], o0, o2); swp(w[5], w[7], o1, o3);
      pw = (unsigned int*)&pb[1];
      pw[0] = o0; pw[1] = o1; pw[2] = o2; pw[3] = o3;
    }

    // rescale old accumulator (alpha per-lane, exact skip when flat)
    if (grew) {
      #pragma unroll
      for (int dh = 0; dh < 2; dh++)
        #pragma unroll
        for (int r = 0; r < 16; r++) oaccT[dh][r] *= alpha;
    }

    // PV: O^T[d][q] += V^T * P, 2 d-halves x 2 key-slices
    #pragma unroll
    for (int dh = 0; dh < 2; dh++)
      #pragma unroll
      for (int s = 0; s < 2; s++)
        oaccT[dh] = __builtin_amdgcn_mfma_f32_32x32x16_bf16(vf[dh][s], pb[s], oaccT[dh], 0, 0, 0);
  };

  // main loop: K prefetched 1 chunk ahead, double-buffered registers
  short8 kfA[4], kfB[4];
  loadK(kfA, 0);
  #pragma unroll
  for (int mcp = 0; mcp < 4; mcp++) {
    loadK(kfB, 2 * mcp + 1);
    step(kfA, 2 * mcp);
    if (mcp < 3) loadK(kfA, 2 * mcp + 2);
    step(kfB, 2 * mcp + 1);
  }

  // cross-wave combine (waves write disjoint regions; one barrier)
  if (hb2 == 0) { mS[wave * 32 + l31] = m_run; lS[wave * 32 + l31] = l_run; }
  #pragma unroll
  for (int dh = 0; dh < 2; dh++)
    #pragma unroll
    for (int r = 0; r < 16; r++) {
      int d = dh * 32 + (r & 3) + 8 * (r >> 2) + 4 * hb2;
      Ow[wave * 2080 + l31 * 65 + d] = oaccT[dh][r];
    }
  __syncthreads();

  bf16* op = oT + (size_t)zb * o_bstride;
  #pragma unroll
  for (int k = 0; k < 8; k++) {
    int idx = k * 256 + tid;
    int q = idx >> 6, d = idx & 63;
    float mstar = mS[q];
    #pragma unroll
    for (int w2 = 1; w2 < 4; w2++) mstar = fmaxf(mstar, mS[w2 * 32 + q]);
    float num = 0.f, den = 0.f;
    #pragma unroll
    for (int w2 = 0; w2 < 4; w2++) {
      float e = __expf(mS[w2 * 32 + q] - mstar);
      den += lS[w2 * 32 + q] * e;
      num += Ow[w2 * 2080 + q * 65 + d] * e;
    }
    op[(size_t)(q0 + q) * 256 + n * 64 + d] = __float2bfloat16(num / den);
  }
}

// proj GEMM on MFMA: out[b][m][l] = Pb[m][:]·o[:][l] + bproj[m] + x, f32 out.
__global__ __launch_bounds__(256) void gemm_proj_mfma(
    const bf16* __restrict__ Pb, const bf16* __restrict__ oT,
    const float* __restrict__ bproj, const float* __restrict__ x,
    float* __restrict__ out, int b_off, size_t o_bstride) {
  __shared__ bf16 As[128][40];
  __shared__ bf16 Bs[128][40];
  int zb = blockIdx.z, b = zb + b_off;
  int m0 = blockIdx.y * 128, l0 = blockIdx.x * 128;
  const bf16* ob = oT + (size_t)zb * o_bstride;
  int tid = threadIdx.x, lane = tid & 63, wave = tid >> 6;
  int l16 = lane & 15, quad = lane >> 4;
  int mi0 = (wave & 1) * 4, nj0 = (wave >> 1) * 4;
  float4v acc[4][4];
  #pragma unroll
  for (int i = 0; i < 4; i++)
    #pragma unroll
    for (int j = 0; j < 4; j++) acc[i][j] = (float4v){0.f, 0.f, 0.f, 0.f};

  for (int kc = 0; kc < 8; kc++) {
    __syncthreads();
    #pragma unroll
    for (int it = 0; it < 2; it++) {
      int s = it * 256 + tid;
      int mm = s >> 2, kk = (s & 3) * 8;
      *(short8*)&As[mm][kk] = *(const short8*)&Pb[(size_t)(m0 + mm) * 256 + kc * 32 + kk];
      *(short8*)&Bs[mm][kk] = *(const short8*)&ob[(size_t)(l0 + mm) * 256 + kc * 32 + kk];
    }
    __syncthreads();
    short8 af[4], bfr[4];
    #pragma unroll
    for (int i = 0; i < 4; i++) af[i]  = *(const short8*)&As[(mi0 + i) * 16 + l16][quad * 8];
    #pragma unroll
    for (int j = 0; j < 4; j++) bfr[j] = *(const short8*)&Bs[(nj0 + j) * 16 + l16][quad * 8];
    #pragma unroll
    for (int i = 0; i < 4; i++)
      #pragma unroll
      for (int j = 0; j < 4; j++)
        acc[i][j] = __builtin_amdgcn_mfma_f32_16x16x32_bf16(af[i], bfr[j], acc[i][j], 0, 0, 0);
  }

  #pragma unroll
  for (int i = 0; i < 4; i++) {
    #pragma unroll
    for (int r = 0; r < 4; r++) {
      int m = m0 + (mi0 + i) * 16 + quad * 4 + r;
      float bias = bproj[m];
      #pragma unroll
      for (int j = 0; j < 4; j++) {
        int l = l0 + (nj0 + j) * 16 + l16;
        size_t idx = (size_t)(b * 256 + m) * 1024 + l;
        out[idx] = acc[i][j][r] + bias + x[idx];
      }
    }
  }
}

extern "C" void kernel_launch(void* const* d_in, const int* in_sizes, int n_in,
                              void* d_out, int out_size, void* d_ws, size_t ws_size,
                              hipStream_t stream) {
  int ix = 0, iga = 1, ibe = 2, iwq = 3, ibq = 4, iwk = 5, ibk = 6,
      iwv = 7, ibv = 8, iwp = 9, ibp = 10;
  if (in_sizes[0] != 4194304) {
    if (in_sizes[10] == 4194304 && in_sizes[1] == 256) {
      ibe = 0; ibk = 1; ibp = 2; ibq = 3; ibv = 4; iga = 5;
      iwk = 6; iwp = 7; iwq = 8; iwv = 9; ix = 10;
    } else if (in_sizes[10] == 4194304 && in_sizes[1] == 65536) {
      ibp = 0; iwp = 1; ibv = 2; iwv = 3; ibk = 4; iwk = 5;
      ibq = 6; iwq = 7; ibe = 8; iga = 9; ix = 10;
    } else {
      for (int i = 0; i < 11; i++) if (in_sizes[i] == 4194304) ix = i;
    }
  }
  const float* x     = (const float*)d_in[ix];
  const float* gamma = (const float*)d_in[iga];
  const float* beta  = (const float*)d_in[ibe];
  const float* wq    = (const float*)d_in[iwq];
  const float* bq    = (const float*)d_in[ibq];
  const float* wk    = (const float*)d_in[iwk];
  const float* bk    = (const float*)d_in[ibk];
  const float* wv    = (const float*)d_in[iwv];
  const float* bv    = (const float*)d_in[ibv];
  const float* wproj = (const float*)d_in[iwp];
  const float* bproj = (const float*)d_in[ibp];
  float* out = (float*)d_out;

  const size_t QKV_B = (size_t)768 * 1024;
  const size_t O_B   = (size_t)256 * 1024;
  char* wsp = (char*)d_ws;
  float2* stats = (float2*)wsp;                        // 4 KB
  bf16* Wb = (bf16*)(wsp + 8192);                      // 384 KB
  bf16* Pb = (bf16*)(wsp + 8192 + 393216);             // 128 KB
  const size_t HT0 = 8192 + 393216 + 131072;
  size_t full_need = HT0 + (size_t)16 * O_B * 2 + (size_t)16 * QKV_B * 2; // ~34.1 MB

  stats_kernel<<<512, 256, 0, stream>>>(x, stats);
  wpack<<<1024, 256, 0, stream>>>(wq, wk, wv, wproj, Wb, Pb);

  if (ws_size >= full_need) {
    bf16* hT  = (bf16*)(wsp + HT0);                    // 8 MB; reused as oT
    bf16* qkv = (bf16*)(wsp + HT0 + 16 * O_B * 2);     // 24 MB
    bf16* oT  = hT;
    gnt_kernel   <<<dim3(16, 4, 16), 256, 0, stream>>>(x, gamma, beta, stats, hT, 0);
    gemm_qkv_mfma<<<dim3(8, 6, 16), 256, 0, stream>>>(hT, Wb, bq, bk, bv, qkv, QKV_B);
    attn_kernel  <<<dim3(32, 4, 16), 256, 0, stream>>>(qkv, oT, QKV_B, O_B);
    gemm_proj_mfma<<<dim3(8, 2, 16), 256, 0, stream>>>(Pb, oT, bproj, x, out, 0, O_B);
  } else {
    bf16* hT  = (bf16*)(wsp + HT0);
    bf16* qkv = (bf16*)(wsp + HT0 + O_B * 2);
    bf16* oT  = hT;
    for (int b = 0; b < 16; b++) {
      gnt_kernel   <<<dim3(16, 4, 1), 256, 0, stream>>>(x, gamma, beta, stats, hT, b);
      gemm_qkv_mfma<<<dim3(8, 6, 1), 256, 0, stream>>>(hT, Wb, bq, bk, bv, qkv, 0);
      attn_kernel  <<<dim3(32, 4, 1), 256, 0, stream>>>(qkv, oT, 0, 0);
      gemm_proj_mfma<<<dim3(8, 2, 1), 256, 0, stream>>>(Pb, oT, bproj, x, out, b, 0);
    }
  }
}

// Round 5
// 191.851 us; speedup vs baseline: 1.1343x; 1.1343x over previous
//
#include <hip/hip_runtime.h>
#include <hip/hip_bf16.h>
#include <stdint.h>

// Problem constants (B=16, C=256, NH=4, D=64, G=32, L=HW=1024)
// Round 21. R20 post-mortem: conflicts 0, LDS bounce gone, VALU cut - attn
// STILL 73us (3rd flat structure). Invariant across all three: scattered
// 16B/lane frag loads (~32 cache lines per wave-inst) -> L2 request-rate
// bound (~12 req/cyc/XCD needed; derived block time 15us vs 2us dataflow).
// This round: FRAGMENT-MAJOR layouts. gemm_qkv writes Q^T/K^T/V in MFMA
// fragment order so every attn load is lane-contiguous 1KB (8 lines, 4x
// fewer L2 requests). Pure permutation, bit-identical math. Also:
//  - exp->exp2 domain: Q pre-scale = 0.125*log2e; all __expf -> exp2f
//    (kills the mul before every transcendental).
//  - fmax/psum serial chains (depth 15) -> balanced trees (depth 4).
// Other kernels unchanged. absmax gate catches any layout error.

typedef __hip_bfloat16 bf16;
typedef __attribute__((ext_vector_type(8))) short short8;
typedef __attribute__((ext_vector_type(4))) float float4v;
typedef __attribute__((ext_vector_type(16))) float float16v;

// fragment-major index for Q^T/K^T per head: element (d, l) of Q[d][l]
// lives at ((l>>5)*4 + (d>>4))*64 + ((d>>3)&1)*32 + (l&31)) * 8 + (d&7)
__device__ __forceinline__ int qk_fidx(int d, int l) {
  return ((((l >> 5) * 4 + (d >> 4)) * 64 + ((d >> 3) & 1) * 32 + (l & 31)) << 3) + (d & 7);
}
// fragment-major index for V per head: element (d, l) of V[d][l]
__device__ __forceinline__ int v_fidx(int d, int l) {
  return (((((((l >> 5) * 2 + (d >> 5)) * 2 + ((l >> 4) & 1)) * 2 + ((l >> 3) & 1)) * 32) + (d & 31)) << 3) + (l & 7);
}

__global__ __launch_bounds__(256) void stats_kernel(const float* __restrict__ x,
    float2* __restrict__ stats) {
  int b = blockIdx.x >> 5, g = blockIdx.x & 31;
  const float* xp = x + (size_t)(b * 256 + g * 8) * 1024;
  float s = 0.f, ss = 0.f;
  for (int i = threadIdx.x; i < 8192; i += 256) {
    float v = xp[i]; s += v; ss += v * v;
  }
  #pragma unroll
  for (int o = 32; o; o >>= 1) { s += __shfl_down(s, o); ss += __shfl_down(ss, o); }
  __shared__ float red[2][4];
  int wid = threadIdx.x >> 6;
  if ((threadIdx.x & 63) == 0) { red[0][wid] = s; red[1][wid] = ss; }
  __syncthreads();
  if (threadIdx.x == 0) {
    s  = red[0][0] + red[0][1] + red[0][2] + red[0][3];
    ss = red[1][0] + red[1][1] + red[1][2] + red[1][3];
    float mean = s * (1.f / 8192.f);
    float var  = ss * (1.f / 8192.f) - mean * mean;
    stats[blockIdx.x] = make_float2(mean, rsqrtf(var + 1e-5f));
  }
}

// GN + transpose: hT[zb][l][c] = GN(x)[b][c][l], bf16.
__global__ __launch_bounds__(256) void gnt_kernel(const float* __restrict__ x,
    const float* __restrict__ gamma, const float* __restrict__ beta,
    const float2* __restrict__ stats, bf16* __restrict__ hT, int b_off) {
  __shared__ float T[64][65];
  int zb = blockIdx.z, b = zb + b_off;
  int c0 = blockIdx.y * 64, l0 = blockIdx.x * 64;
  const float* xb = x + (size_t)b * 262144;
  const float2* st = stats + b * 32;
  int tid = threadIdx.x;
  for (int i = tid; i < 4096; i += 256) {
    int cl = i >> 6, ll = i & 63;
    int c = c0 + cl;
    float2 s2 = st[c >> 3];
    T[cl][ll] = (xb[(size_t)c * 1024 + l0 + ll] - s2.x) * s2.y * gamma[c] + beta[c];
  }
  __syncthreads();
  bf16* hb = hT + (size_t)zb * 262144;
  for (int i = tid; i < 4096; i += 256) {
    int ll = i >> 6, cl = i & 63;
    hb[(size_t)(l0 + ll) * 256 + c0 + cl] = __float2bfloat16(T[cl][ll]);
  }
}

__global__ __launch_bounds__(256) void wpack(const float* __restrict__ wq,
    const float* __restrict__ wk, const float* __restrict__ wv,
    const float* __restrict__ wp, bf16* __restrict__ Wb, bf16* __restrict__ Pb) {
  int i = blockIdx.x * 256 + threadIdx.x;        // 262144 total
  if (i < 196608) {
    int r = i >> 8, c = i & 255;
    const float* src = (r < 256) ? wq : (r < 512) ? wk : wv;
    Wb[i] = __float2bfloat16(src[(r & 255) * 256 + c]);
  } else {
    int j = i - 196608;
    Pb[j] = __float2bfloat16(wp[j]);
  }
}

// qkv GEMM on MFMA: C[m][l] = Wb[m][:]·h[:][l] + bias. B^T = hT rows.
// Epilogue writes Q/K/V in attn FRAGMENT-MAJOR layouts (see qk_fidx/v_fidx).
// Q pre-scaled by 0.125*log2(e) (exp2-domain softmax).
__global__ __launch_bounds__(256) void gemm_qkv_mfma(
    const bf16* __restrict__ hT, const bf16* __restrict__ Wb,
    const float* __restrict__ bq, const float* __restrict__ bk,
    const float* __restrict__ bv,
    bf16* __restrict__ qkv, size_t qkv_bstride) {
  __shared__ bf16 As[128][40];
  __shared__ bf16 Bs[128][40];
  int zb = blockIdx.z;
  int m0 = blockIdx.y * 128, l0 = blockIdx.x * 128;
  const bf16* hb = hT + (size_t)zb * 262144;
  int tid = threadIdx.x, lane = tid & 63, wave = tid >> 6;
  int l16 = lane & 15, quad = lane >> 4;
  int mi0 = (wave & 1) * 4, nj0 = (wave >> 1) * 4;
  float4v acc[4][4];
  #pragma unroll
  for (int i = 0; i < 4; i++)
    #pragma unroll
    for (int j = 0; j < 4; j++) acc[i][j] = (float4v){0.f, 0.f, 0.f, 0.f};

  for (int kc = 0; kc < 8; kc++) {
    __syncthreads();
    #pragma unroll
    for (int it = 0; it < 2; it++) {
      int s = it * 256 + tid;
      int mm = s >> 2, kk = (s & 3) * 8;
      *(short8*)&As[mm][kk] = *(const short8*)&Wb[(size_t)(m0 + mm) * 256 + kc * 32 + kk];
      *(short8*)&Bs[mm][kk] = *(const short8*)&hb[(size_t)(l0 + mm) * 256 + kc * 32 + kk];
    }
    __syncthreads();
    short8 af[4], bfr[4];
    #pragma unroll
    for (int i = 0; i < 4; i++) af[i]  = *(const short8*)&As[(mi0 + i) * 16 + l16][quad * 8];
    #pragma unroll
    for (int j = 0; j < 4; j++) bfr[j] = *(const short8*)&Bs[(nj0 + j) * 16 + l16][quad * 8];
    #pragma unroll
    for (int i = 0; i < 4; i++)
      #pragma unroll
      for (int j = 0; j < 4; j++)
        acc[i][j] = __builtin_amdgcn_mfma_f32_16x16x32_bf16(af[i], bfr[j], acc[i][j], 0, 0, 0);
  }

  bf16* Cp = qkv + (size_t)zb * qkv_bstride;
  int sec = m0 >> 8;
  const float* bptr = (sec == 0) ? bq : (sec == 1) ? bk : bv;
  float osc = (sec == 0) ? 0.125f * 1.4426950408889634f : 1.0f;
  #pragma unroll
  for (int i = 0; i < 4; i++) {
    #pragma unroll
    for (int r = 0; r < 4; r++) {
      int m = m0 + (mi0 + i) * 16 + quad * 4 + r;
      int rr = m & 255;
      float bias = bptr[rr];
      int n = rr >> 6, d = rr & 63;
      if (sec <= 1) {
        bf16* Tp = Cp + sec * 262144 + n * 65536;       // frag-major Q/K
        #pragma unroll
        for (int j = 0; j < 4; j++) {
          int l = l0 + (nj0 + j) * 16 + l16;
          Tp[qk_fidx(d, l)] = __float2bfloat16((acc[i][j][r] + bias) * osc);
        }
      } else {
        bf16* Vf = Cp + 524288 + n * 65536;             // frag-major V
        #pragma unroll
        for (int j = 0; j < 4; j++) {
          int l = l0 + (nj0 + j) * 16 + l16;
          Vf[v_fidx(d, l)] = __float2bfloat16(acc[i][j][r] + bias);
        }
      }
    }
  }
}

// Flash MFMA attention, 32x32 MFMA + permlane P-redistribution + frag-major
// coalesced loads (1KB/inst). Block = (b, head, 32 q-rows); 4 waves each own
// a 32-key slice of every 128-key chunk. Lane owns one q column. exp2 domain.
__global__ __launch_bounds__(256) void attn_kernel(
    const bf16* __restrict__ qkv, bf16* __restrict__ oT,
    size_t qkv_bstride, size_t o_bstride) {
  __shared__ __align__(16) char lds_raw[34304];
  float* Ow = (float*)lds_raw;                   // combine: 4x32x65 f32 = 33280 B
  float* mS = (float*)(lds_raw + 33280);         // [4][32]
  float* lS = (float*)(lds_raw + 33792);         // [4][32]

  // Block id decode: full path (gridDim.z==16) uses an XCD swizzle so all
  // 32 q-blocks of head h land on wgid = h&7 (mod 8) -> one XCD's L2.
  int zb, n, g;                                  // g = q-group (q0 = g*32)
  {
    int f = blockIdx.x + (blockIdx.y << 5) + (blockIdx.z << 7);
    if (gridDim.z == 16) {
      int c = f & 7, t2 = f >> 3;
      int h = ((t2 >> 5) << 3) + c;
      zb = h >> 2; n = h & 3; g = t2 & 31;
    } else {
      zb = blockIdx.z; n = blockIdx.y; g = blockIdx.x;
    }
  }
  int q0 = g << 5;
  const bf16* base = qkv + (size_t)zb * qkv_bstride;
  const bf16* Qf = base + n * 65536;                     // frag-major, exp2-scaled
  const bf16* Kf = base + 262144 + n * 65536;            // frag-major
  const bf16* Vf = base + 524288 + n * 65536;            // frag-major
  int tid = threadIdx.x;
  int lane = tid & 63, wave = tid >> 6;
  int l31 = lane & 31, hb2 = lane >> 5;

  // Q B-frags: coalesced 1KB loads
  short8 qb[4];
  #pragma unroll
  for (int ds = 0; ds < 4; ds++)
    qb[ds] = *(const short8*)&Qf[(((g * 4 + ds) << 6) + lane) << 3];

  float m_run = -1e30f, l_run = 0.f;
  float16v oaccT[2];
  #pragma unroll
  for (int dh = 0; dh < 2; dh++)
    #pragma unroll
    for (int r = 0; r < 16; r++) oaccT[dh][r] = 0.f;

  auto swp = [&](unsigned int a, unsigned int b, unsigned int& o0, unsigned int& o1) {
#if __has_builtin(__builtin_amdgcn_permlane32_swap)
    auto rr = __builtin_amdgcn_permlane32_swap((int)a, (int)b, false, false);
    o0 = (unsigned int)rr[0]; o1 = (unsigned int)rr[1];
#else
    unsigned int sa = (unsigned int)__shfl_xor((int)a, 32, 64);
    unsigned int sb = (unsigned int)__shfl_xor((int)b, 32, 64);
    o0 = hb2 ? sb : a;
    o1 = hb2 ? b : sa;
#endif
  };

  auto loadK = [&](short8 (&kf)[4], int mc) {
    int kg = mc * 4 + wave;
    #pragma unroll
    for (int ds = 0; ds < 4; ds++)
      kf[ds] = *(const short8*)&Kf[(((kg * 4 + ds) << 6) + lane) << 3];
  };

  auto step = [&](short8 (&kf)[4], int mc) {
    int kg = mc * 4 + wave;
    // V A-frags: coalesced 1KB loads, issued early (hide under S+softmax)
    short8 vf[2][2];
    #pragma unroll
    for (int dh = 0; dh < 2; dh++)
      #pragma unroll
      for (int s = 0; s < 2; s++)
        vf[dh][s] = *(const short8*)&Vf[((((kg * 2 + dh) * 2 + s) << 6) + lane) << 3];

    // S[key 32][q 32] over d=64: 4 chained MFMAs
    float16v sacc;
    #pragma unroll
    for (int r = 0; r < 16; r++) sacc[r] = 0.f;
    #pragma unroll
    for (int ds = 0; ds < 4; ds++)
      sacc = __builtin_amdgcn_mfma_f32_32x32x16_bf16(kf[ds], qb[ds], sacc, 0, 0, 0);

    // online softmax (exp2 domain): lane owns q=l31; balanced max tree
    float tm[8];
    #pragma unroll
    for (int i = 0; i < 8; i++) tm[i] = fmaxf(sacc[2 * i], sacc[2 * i + 1]);
    #pragma unroll
    for (int i = 0; i < 4; i++) tm[i] = fmaxf(tm[i], tm[i + 4]);
    tm[0] = fmaxf(tm[0], tm[2]); tm[1] = fmaxf(tm[1], tm[3]);
    float cmax = fmaxf(tm[0], tm[1]);
    cmax = fmaxf(cmax, __shfl_xor(cmax, 32, 64));
    float mnew = fmaxf(m_run, cmax);
    int grew = __any(mnew > m_run);
    float alpha = exp2f(m_run - mnew);
    float p[16];
    #pragma unroll
    for (int r = 0; r < 16; r++) p[r] = exp2f(sacc[r] - mnew);
    float ts[8];
    #pragma unroll
    for (int i = 0; i < 8; i++) ts[i] = p[2 * i] + p[2 * i + 1];
    #pragma unroll
    for (int i = 0; i < 4; i++) ts[i] += ts[i + 4];
    ts[0] += ts[2]; ts[1] += ts[3];
    float psum = ts[0] + ts[1];
    psum += __shfl_xor(psum, 32, 64);
    l_run = l_run * alpha + psum;
    m_run = mnew;

    // P -> PV B-frags in-register: pack pairs, permlane32_swap halves.
    unsigned int w[8];
    #pragma unroll
    for (int i = 0; i < 8; i++) {
      bf16 plo = __float2bfloat16(p[2 * i]);
      bf16 phi = __float2bfloat16(p[2 * i + 1]);
      w[i] = (unsigned int)*(unsigned short*)&plo |
             ((unsigned int)*(unsigned short*)&phi << 16);
    }
    short8 pb[2];
    {
      unsigned int o0, o1, o2, o3;
      swp(w[0], w[2], o0, o2); swp(w[1], w[3], o1, o3);
      unsigned int* pw = (unsigned int*)&pb[0];
      pw[0] = o0; pw[1] = o1; pw[2] = o2; pw[3] = o3;
      swp(w[4], w[6], o0, o2); swp(w[5], w[7], o1, o3);
      pw = (unsigned int*)&pb[1];
      pw[0] = o0; pw[1] = o1; pw[2] = o2; pw[3] = o3;
    }

    // rescale old accumulator (alpha per-lane, exact skip when flat)
    if (grew) {
      #pragma unroll
      for (int dh = 0; dh < 2; dh++)
        #pragma unroll
        for (int r = 0; r < 16; r++) oaccT[dh][r] *= alpha;
    }

    // PV: O^T[d][q] += V^T * P, 2 d-halves x 2 key-slices
    #pragma unroll
    for (int dh = 0; dh < 2; dh++)
      #pragma unroll
      for (int s = 0; s < 2; s++)
        oaccT[dh] = __builtin_amdgcn_mfma_f32_32x32x16_bf16(vf[dh][s], pb[s], oaccT[dh], 0, 0, 0);
  };

  // main loop: K prefetched 1 chunk ahead, double-buffered registers
  short8 kfA[4], kfB[4];
  loadK(kfA, 0);
  #pragma unroll
  for (int mcp = 0; mcp < 4; mcp++) {
    loadK(kfB, 2 * mcp + 1);
    step(kfA, 2 * mcp);
    if (mcp < 3) loadK(kfA, 2 * mcp + 2);
    step(kfB, 2 * mcp + 1);
  }

  // cross-wave combine (waves write disjoint regions; one barrier)
  if (hb2 == 0) { mS[wave * 32 + l31] = m_run; lS[wave * 32 + l31] = l_run; }
  #pragma unroll
  for (int dh = 0; dh < 2; dh++)
    #pragma unroll
    for (int r = 0; r < 16; r++) {
      int d = dh * 32 + (r & 3) + 8 * (r >> 2) + 4 * hb2;
      Ow[wave * 2080 + l31 * 65 + d] = oaccT[dh][r];
    }
  __syncthreads();

  bf16* op = oT + (size_t)zb * o_bstride;
  #pragma unroll
  for (int k = 0; k < 8; k++) {
    int idx = k * 256 + tid;
    int q = idx >> 6, d = idx & 63;
    float mstar = mS[q];
    #pragma unroll
    for (int w2 = 1; w2 < 4; w2++) mstar = fmaxf(mstar, mS[w2 * 32 + q]);
    float num = 0.f, den = 0.f;
    #pragma unroll
    for (int w2 = 0; w2 < 4; w2++) {
      float e = exp2f(mS[w2 * 32 + q] - mstar);
      den += lS[w2 * 32 + q] * e;
      num += Ow[w2 * 2080 + q * 65 + d] * e;
    }
    op[(size_t)(q0 + q) * 256 + n * 64 + d] = __float2bfloat16(num / den);
  }
}

// proj GEMM on MFMA: out[b][m][l] = Pb[m][:]·o[:][l] + bproj[m] + x, f32 out.
__global__ __launch_bounds__(256) void gemm_proj_mfma(
    const bf16* __restrict__ Pb, const bf16* __restrict__ oT,
    const float* __restrict__ bproj, const float* __restrict__ x,
    float* __restrict__ out, int b_off, size_t o_bstride) {
  __shared__ bf16 As[128][40];
  __shared__ bf16 Bs[128][40];
  int zb = blockIdx.z, b = zb + b_off;
  int m0 = blockIdx.y * 128, l0 = blockIdx.x * 128;
  const bf16* ob = oT + (size_t)zb * o_bstride;
  int tid = threadIdx.x, lane = tid & 63, wave = tid >> 6;
  int l16 = lane & 15, quad = lane >> 4;
  int mi0 = (wave & 1) * 4, nj0 = (wave >> 1) * 4;
  float4v acc[4][4];
  #pragma unroll
  for (int i = 0; i < 4; i++)
    #pragma unroll
    for (int j = 0; j < 4; j++) acc[i][j] = (float4v){0.f, 0.f, 0.f, 0.f};

  for (int kc = 0; kc < 8; kc++) {
    __syncthreads();
    #pragma unroll
    for (int it = 0; it < 2; it++) {
      int s = it * 256 + tid;
      int mm = s >> 2, kk = (s & 3) * 8;
      *(short8*)&As[mm][kk] = *(const short8*)&Pb[(size_t)(m0 + mm) * 256 + kc * 32 + kk];
      *(short8*)&Bs[mm][kk] = *(const short8*)&ob[(size_t)(l0 + mm) * 256 + kc * 32 + kk];
    }
    __syncthreads();
    short8 af[4], bfr[4];
    #pragma unroll
    for (int i = 0; i < 4; i++) af[i]  = *(const short8*)&As[(mi0 + i) * 16 + l16][quad * 8];
    #pragma unroll
    for (int j = 0; j < 4; j++) bfr[j] = *(const short8*)&Bs[(nj0 + j) * 16 + l16][quad * 8];
    #pragma unroll
    for (int i = 0; i < 4; i++)
      #pragma unroll
      for (int j = 0; j < 4; j++)
        acc[i][j] = __builtin_amdgcn_mfma_f32_16x16x32_bf16(af[i], bfr[j], acc[i][j], 0, 0, 0);
  }

  #pragma unroll
  for (int i = 0; i < 4; i++) {
    #pragma unroll
    for (int r = 0; r < 4; r++) {
      int m = m0 + (mi0 + i) * 16 + quad * 4 + r;
      float bias = bproj[m];
      #pragma unroll
      for (int j = 0; j < 4; j++) {
        int l = l0 + (nj0 + j) * 16 + l16;
        size_t idx = (size_t)(b * 256 + m) * 1024 + l;
        out[idx] = acc[i][j][r] + bias + x[idx];
      }
    }
  }
}

extern "C" void kernel_launch(void* const* d_in, const int* in_sizes, int n_in,
                              void* d_out, int out_size, void* d_ws, size_t ws_size,
                              hipStream_t stream) {
  int ix = 0, iga = 1, ibe = 2, iwq = 3, ibq = 4, iwk = 5, ibk = 6,
      iwv = 7, ibv = 8, iwp = 9, ibp = 10;
  if (in_sizes[0] != 4194304) {
    if (in_sizes[10] == 4194304 && in_sizes[1] == 256) {
      ibe = 0; ibk = 1; ibp = 2; ibq = 3; ibv = 4; iga = 5;
      iwk = 6; iwp = 7; iwq = 8; iwv = 9; ix = 10;
    } else if (in_sizes[10] == 4194304 && in_sizes[1] == 65536) {
      ibp = 0; iwp = 1; ibv = 2; iwv = 3; ibk = 4; iwk = 5;
      ibq = 6; iwq = 7; ibe = 8; iga = 9; ix = 10;
    } else {
      for (int i = 0; i < 11; i++) if (in_sizes[i] == 4194304) ix = i;
    }
  }
  const float* x     = (const float*)d_in[ix];
  const float* gamma = (const float*)d_in[iga];
  const float* beta  = (const float*)d_in[ibe];
  const float* wq    = (const float*)d_in[iwq];
  const float* bq    = (const float*)d_in[ibq];
  const float* wk    = (const float*)d_in[iwk];
  const float* bk    = (const float*)d_in[ibk];
  const float* wv    = (const float*)d_in[iwv];
  const float* bv    = (const float*)d_in[ibv];
  const float* wproj = (const float*)d_in[iwp];
  const float* bproj = (const float*)d_in[ibp];
  float* out = (float*)d_out;

  const size_t QKV_B = (size_t)768 * 1024;
  const size_t O_B   = (size_t)256 * 1024;
  char* wsp = (char*)d_ws;
  float2* stats = (float2*)wsp;                        // 4 KB
  bf16* Wb = (bf16*)(wsp + 8192);                      // 384 KB
  bf16* Pb = (bf16*)(wsp + 8192 + 393216);             // 128 KB
  const size_t HT0 = 8192 + 393216 + 131072;
  size_t full_need = HT0 + (size_t)16 * O_B * 2 + (size_t)16 * QKV_B * 2; // ~34.1 MB

  stats_kernel<<<512, 256, 0, stream>>>(x, stats);
  wpack<<<1024, 256, 0, stream>>>(wq, wk, wv, wproj, Wb, Pb);

  if (ws_size >= full_need) {
    bf16* hT  = (bf16*)(wsp + HT0);                    // 8 MB; reused as oT
    bf16* qkv = (bf16*)(wsp + HT0 + 16 * O_B * 2);     // 24 MB
    bf16* oT  = hT;
    gnt_kernel   <<<dim3(16, 4, 16), 256, 0, stream>>>(x, gamma, beta, stats, hT, 0);
    gemm_qkv_mfma<<<dim3(8, 6, 16), 256, 0, stream>>>(hT, Wb, bq, bk, bv, qkv, QKV_B);
    attn_kernel  <<<dim3(32, 4, 16), 256, 0, stream>>>(qkv, oT, QKV_B, O_B);
    gemm_proj_mfma<<<dim3(8, 2, 16), 256, 0, stream>>>(Pb, oT, bproj, x, out, 0, O_B);
  } else {
    bf16* hT  = (bf16*)(wsp + HT0);
    bf16* qkv = (bf16*)(wsp + HT0 + O_B * 2);
    bf16* oT  = hT;
    for (int b = 0; b < 16; b++) {
      gnt_kernel   <<<dim3(16, 4, 1), 256, 0, stream>>>(x, gamma, beta, stats, hT, b);
      gemm_qkv_mfma<<<dim3(8, 6, 1), 256, 0, stream>>>(hT, Wb, bq, bk, bv, qkv, 0);
      attn_kernel  <<<dim3(32, 4, 1), 256, 0, stream>>>(qkv, oT, 0, 0);
      gemm_proj_mfma<<<dim3(8, 2, 1), 256, 0, stream>>>(Pb, oT, bproj, x, out, b, 0);
    }
  }
}

// Round 6
// 186.420 us; speedup vs baseline: 1.1673x; 1.0291x over previous
//
#include <hip/hip_runtime.h>
#include <hip/hip_bf16.h>
#include <stdint.h>

// Problem constants (B=16, C=256, NH=4, D=64, G=32, L=HW=1024)
// Round 22. R21 post-mortem: frag-major coalescing WORKED (73->56.7us,
// VALUBusy 41->71%) -> now VALU-inst-bound. This round removes VALU work:
//  - Wave-independent restructure: each wave owns 32 q over ALL 1024 keys
//    (block = 128 q, grid 512). Same total L2 traffic (waves split q instead
//    of keys). Cross-wave combine epilogue DELETED: no barrier, no m/l LDS,
//    no 8x(4exp2+4fma+div) per thread; per-wave in-register normalize.
//  - Defer-max (T13, THR=8, exp2 domain): rescale only when cmax exceeds
//    m_run+8 -> the 32-mul+exp2 rescale fires ~once per wave instead of
//    every chunk. p<=2^8; bf16 relative precision unchanged (num and den
//    scale together) -> numerics equivalent.
//  - Epilogue: tiny per-wave LDS bounce [32][65] f32 (2-way banks, free)
//    for coalesced 128B stores.
// XCD swizzle kept: 8 q-blocks of head h -> XCD h%8. All other kernels
// unchanged from R21 (green, absmax 0.03125).

typedef __hip_bfloat16 bf16;
typedef __attribute__((ext_vector_type(8))) short short8;
typedef __attribute__((ext_vector_type(4))) float float4v;
typedef __attribute__((ext_vector_type(16))) float float16v;

// fragment-major index for Q^T/K^T per head: element (d, l) of Q[d][l]
__device__ __forceinline__ int qk_fidx(int d, int l) {
  return ((((l >> 5) * 4 + (d >> 4)) * 64 + ((d >> 3) & 1) * 32 + (l & 31)) << 3) + (d & 7);
}
// fragment-major index for V per head: element (d, l) of V[d][l]
__device__ __forceinline__ int v_fidx(int d, int l) {
  return (((((((l >> 5) * 2 + (d >> 5)) * 2 + ((l >> 4) & 1)) * 2 + ((l >> 3) & 1)) * 32) + (d & 31)) << 3) + (l & 7);
}

__global__ __launch_bounds__(256) void stats_kernel(const float* __restrict__ x,
    float2* __restrict__ stats) {
  int b = blockIdx.x >> 5, g = blockIdx.x & 31;
  const float* xp = x + (size_t)(b * 256 + g * 8) * 1024;
  float s = 0.f, ss = 0.f;
  for (int i = threadIdx.x; i < 8192; i += 256) {
    float v = xp[i]; s += v; ss += v * v;
  }
  #pragma unroll
  for (int o = 32; o; o >>= 1) { s += __shfl_down(s, o); ss += __shfl_down(ss, o); }
  __shared__ float red[2][4];
  int wid = threadIdx.x >> 6;
  if ((threadIdx.x & 63) == 0) { red[0][wid] = s; red[1][wid] = ss; }
  __syncthreads();
  if (threadIdx.x == 0) {
    s  = red[0][0] + red[0][1] + red[0][2] + red[0][3];
    ss = red[1][0] + red[1][1] + red[1][2] + red[1][3];
    float mean = s * (1.f / 8192.f);
    float var  = ss * (1.f / 8192.f) - mean * mean;
    stats[blockIdx.x] = make_float2(mean, rsqrtf(var + 1e-5f));
  }
}

// GN + transpose: hT[zb][l][c] = GN(x)[b][c][l], bf16.
__global__ __launch_bounds__(256) void gnt_kernel(const float* __restrict__ x,
    const float* __restrict__ gamma, const float* __restrict__ beta,
    const float2* __restrict__ stats, bf16* __restrict__ hT, int b_off) {
  __shared__ float T[64][65];
  int zb = blockIdx.z, b = zb + b_off;
  int c0 = blockIdx.y * 64, l0 = blockIdx.x * 64;
  const float* xb = x + (size_t)b * 262144;
  const float2* st = stats + b * 32;
  int tid = threadIdx.x;
  for (int i = tid; i < 4096; i += 256) {
    int cl = i >> 6, ll = i & 63;
    int c = c0 + cl;
    float2 s2 = st[c >> 3];
    T[cl][ll] = (xb[(size_t)c * 1024 + l0 + ll] - s2.x) * s2.y * gamma[c] + beta[c];
  }
  __syncthreads();
  bf16* hb = hT + (size_t)zb * 262144;
  for (int i = tid; i < 4096; i += 256) {
    int ll = i >> 6, cl = i & 63;
    hb[(size_t)(l0 + ll) * 256 + c0 + cl] = __float2bfloat16(T[cl][ll]);
  }
}

__global__ __launch_bounds__(256) void wpack(const float* __restrict__ wq,
    const float* __restrict__ wk, const float* __restrict__ wv,
    const float* __restrict__ wp, bf16* __restrict__ Wb, bf16* __restrict__ Pb) {
  int i = blockIdx.x * 256 + threadIdx.x;        // 262144 total
  if (i < 196608) {
    int r = i >> 8, c = i & 255;
    const float* src = (r < 256) ? wq : (r < 512) ? wk : wv;
    Wb[i] = __float2bfloat16(src[(r & 255) * 256 + c]);
  } else {
    int j = i - 196608;
    Pb[j] = __float2bfloat16(wp[j]);
  }
}

// qkv GEMM on MFMA: C[m][l] = Wb[m][:]·h[:][l] + bias. B^T = hT rows.
// Epilogue writes Q/K/V in attn FRAGMENT-MAJOR layouts (see qk_fidx/v_fidx).
// Q pre-scaled by 0.125*log2(e) (exp2-domain softmax).
__global__ __launch_bounds__(256) void gemm_qkv_mfma(
    const bf16* __restrict__ hT, const bf16* __restrict__ Wb,
    const float* __restrict__ bq, const float* __restrict__ bk,
    const float* __restrict__ bv,
    bf16* __restrict__ qkv, size_t qkv_bstride) {
  __shared__ bf16 As[128][40];
  __shared__ bf16 Bs[128][40];
  int zb = blockIdx.z;
  int m0 = blockIdx.y * 128, l0 = blockIdx.x * 128;
  const bf16* hb = hT + (size_t)zb * 262144;
  int tid = threadIdx.x, lane = tid & 63, wave = tid >> 6;
  int l16 = lane & 15, quad = lane >> 4;
  int mi0 = (wave & 1) * 4, nj0 = (wave >> 1) * 4;
  float4v acc[4][4];
  #pragma unroll
  for (int i = 0; i < 4; i++)
    #pragma unroll
    for (int j = 0; j < 4; j++) acc[i][j] = (float4v){0.f, 0.f, 0.f, 0.f};

  for (int kc = 0; kc < 8; kc++) {
    __syncthreads();
    #pragma unroll
    for (int it = 0; it < 2; it++) {
      int s = it * 256 + tid;
      int mm = s >> 2, kk = (s & 3) * 8;
      *(short8*)&As[mm][kk] = *(const short8*)&Wb[(size_t)(m0 + mm) * 256 + kc * 32 + kk];
      *(short8*)&Bs[mm][kk] = *(const short8*)&hb[(size_t)(l0 + mm) * 256 + kc * 32 + kk];
    }
    __syncthreads();
    short8 af[4], bfr[4];
    #pragma unroll
    for (int i = 0; i < 4; i++) af[i]  = *(const short8*)&As[(mi0 + i) * 16 + l16][quad * 8];
    #pragma unroll
    for (int j = 0; j < 4; j++) bfr[j] = *(const short8*)&Bs[(nj0 + j) * 16 + l16][quad * 8];
    #pragma unroll
    for (int i = 0; i < 4; i++)
      #pragma unroll
      for (int j = 0; j < 4; j++)
        acc[i][j] = __builtin_amdgcn_mfma_f32_16x16x32_bf16(af[i], bfr[j], acc[i][j], 0, 0, 0);
  }

  bf16* Cp = qkv + (size_t)zb * qkv_bstride;
  int sec = m0 >> 8;
  const float* bptr = (sec == 0) ? bq : (sec == 1) ? bk : bv;
  float osc = (sec == 0) ? 0.125f * 1.4426950408889634f : 1.0f;
  #pragma unroll
  for (int i = 0; i < 4; i++) {
    #pragma unroll
    for (int r = 0; r < 4; r++) {
      int m = m0 + (mi0 + i) * 16 + quad * 4 + r;
      int rr = m & 255;
      float bias = bptr[rr];
      int n = rr >> 6, d = rr & 63;
      if (sec <= 1) {
        bf16* Tp = Cp + sec * 262144 + n * 65536;       // frag-major Q/K
        #pragma unroll
        for (int j = 0; j < 4; j++) {
          int l = l0 + (nj0 + j) * 16 + l16;
          Tp[qk_fidx(d, l)] = __float2bfloat16((acc[i][j][r] + bias) * osc);
        }
      } else {
        bf16* Vf = Cp + 524288 + n * 65536;             // frag-major V
        #pragma unroll
        for (int j = 0; j < 4; j++) {
          int l = l0 + (nj0 + j) * 16 + l16;
          Vf[v_fidx(d, l)] = __float2bfloat16(acc[i][j][r] + bias);
        }
      }
    }
  }
}

// Flash MFMA attention, wave-independent: each wave owns 32 q-rows over all
// 1024 keys. 32x32 MFMA, permlane P-redistribution, frag-major coalesced
// loads, defer-max (THR=8). No barriers; LDS only for the coalesced store
// bounce. Grid 512 blocks (full path), XCD-swizzled per head.
__global__ __launch_bounds__(256) void attn_kernel(
    const bf16* __restrict__ qkv, bf16* __restrict__ oT,
    size_t qkv_bstride, size_t o_bstride) {
  __shared__ __align__(16) float Ow[4][2080];    // per-wave [32 q][65] f32

  int zb, n, gg;
  {
    int f = blockIdx.x + (blockIdx.y << 3) + (blockIdx.z << 5);
    if (gridDim.z == 16) {
      int h = f & 63;                             // wgid%8 == h%8 -> XCD locality
      zb = h >> 2; n = h & 3; gg = f >> 6;
    } else {
      zb = blockIdx.z; n = blockIdx.y; gg = blockIdx.x;
    }
  }
  const bf16* base = qkv + (size_t)zb * qkv_bstride;
  const bf16* Qf = base + n * 65536;              // frag-major, exp2-scaled
  const bf16* Kf = base + 262144 + n * 65536;     // frag-major
  const bf16* Vf = base + 524288 + n * 65536;     // frag-major
  int tid = threadIdx.x;
  int lane = tid & 63, wave = tid >> 6;
  int l31 = lane & 31, hb2 = lane >> 5;
  int g = gg * 4 + wave;                          // q-tile 0..31
  int q0 = g << 5;

  // Q B-frags: coalesced 1KB loads
  short8 qb[4];
  #pragma unroll
  for (int ds = 0; ds < 4; ds++)
    qb[ds] = *(const short8*)&Qf[(((g * 4 + ds) << 6) + lane) << 3];

  float m_run = -1e30f, l_run = 0.f;
  float16v oaccT[2];
  #pragma unroll
  for (int dh = 0; dh < 2; dh++)
    #pragma unroll
    for (int r = 0; r < 16; r++) oaccT[dh][r] = 0.f;

  auto swp = [&](unsigned int a, unsigned int b, unsigned int& o0, unsigned int& o1) {
#if __has_builtin(__builtin_amdgcn_permlane32_swap)
    auto rr = __builtin_amdgcn_permlane32_swap((int)a, (int)b, false, false);
    o0 = (unsigned int)rr[0]; o1 = (unsigned int)rr[1];
#else
    unsigned int sa = (unsigned int)__shfl_xor((int)a, 32, 64);
    unsigned int sb = (unsigned int)__shfl_xor((int)b, 32, 64);
    o0 = hb2 ? sb : a;
    o1 = hb2 ? b : sa;
#endif
  };

  for (int kt = 0; kt < 32; kt++) {
    // K B-frags + V A-frags: coalesced 1KB loads
    short8 kf[4];
    #pragma unroll
    for (int ds = 0; ds < 4; ds++)
      kf[ds] = *(const short8*)&Kf[(((kt * 4 + ds) << 6) + lane) << 3];
    short8 vf[2][2];
    #pragma unroll
    for (int dh = 0; dh < 2; dh++)
      #pragma unroll
      for (int s = 0; s < 2; s++)
        vf[dh][s] = *(const short8*)&Vf[((((kt * 2 + dh) * 2 + s) << 6) + lane) << 3];

    // S[key 32][q 32] over d=64: 4 chained MFMAs
    float16v sacc;
    #pragma unroll
    for (int r = 0; r < 16; r++) sacc[r] = 0.f;
    #pragma unroll
    for (int ds = 0; ds < 4; ds++)
      sacc = __builtin_amdgcn_mfma_f32_32x32x16_bf16(kf[ds], qb[ds], sacc, 0, 0, 0);

    // chunk max (balanced tree + cross-half)
    float t0 = fmaxf(fmaxf(sacc[0], sacc[1]), fmaxf(sacc[2], sacc[3]));
    float t1 = fmaxf(fmaxf(sacc[4], sacc[5]), fmaxf(sacc[6], sacc[7]));
    float t2 = fmaxf(fmaxf(sacc[8], sacc[9]), fmaxf(sacc[10], sacc[11]));
    float t3 = fmaxf(fmaxf(sacc[12], sacc[13]), fmaxf(sacc[14], sacc[15]));
    float cmax = fmaxf(fmaxf(t0, t1), fmaxf(t2, t3));
    cmax = fmaxf(cmax, __shfl_xor(cmax, 32, 64));

    // defer-max: rescale only when the bound would be exceeded (exp2 domain)
    if (__any(cmax > m_run + 8.f)) {
      float mnew = fmaxf(m_run, cmax);
      float alpha = exp2f(m_run - mnew);
      #pragma unroll
      for (int dh = 0; dh < 2; dh++)
        #pragma unroll
        for (int r = 0; r < 16; r++) oaccT[dh][r] *= alpha;
      l_run *= alpha;
      m_run = mnew;
    }

    // p = exp2(s - m_run), bounded by 2^8
    float p[16];
    #pragma unroll
    for (int r = 0; r < 16; r++) p[r] = exp2f(sacc[r] - m_run);
    float s0 = (p[0] + p[1]) + (p[2] + p[3]);
    float s1 = (p[4] + p[5]) + (p[6] + p[7]);
    float s2 = (p[8] + p[9]) + (p[10] + p[11]);
    float s3 = (p[12] + p[13]) + (p[14] + p[15]);
    float psum = (s0 + s1) + (s2 + s3);
    psum += __shfl_xor(psum, 32, 64);
    l_run += psum;

    // P -> PV B-frags in-register: pack pairs, permlane32_swap halves
    unsigned int w[8];
    #pragma unroll
    for (int i = 0; i < 8; i++) {
      bf16 plo = __float2bfloat16(p[2 * i]);
      bf16 phi = __float2bfloat16(p[2 * i + 1]);
      w[i] = (unsigned int)*(unsigned short*)&plo |
             ((unsigned int)*(unsigned short*)&phi << 16);
    }
    short8 pb[2];
    {
      unsigned int o0, o1, o2, o3;
      swp(w[0], w[2], o0, o2); swp(w[1], w[3], o1, o3);
      unsigned int* pw = (unsigned int*)&pb[0];
      pw[0] = o0; pw[1] = o1; pw[2] = o2; pw[3] = o3;
      swp(w[4], w[6], o0, o2); swp(w[5], w[7], o1, o3);
      pw = (unsigned int*)&pb[1];
      pw[0] = o0; pw[1] = o1; pw[2] = o2; pw[3] = o3;
    }

    // PV: O^T[d][q] += V^T * P, 2 d-halves x 2 key-slices
    #pragma unroll
    for (int dh = 0; dh < 2; dh++)
      #pragma unroll
      for (int s = 0; s < 2; s++)
        oaccT[dh] = __builtin_amdgcn_mfma_f32_32x32x16_bf16(vf[dh][s], pb[s], oaccT[dh], 0, 0, 0);
  }

  // per-wave epilogue: normalize in-register, LDS bounce for coalesced store
  float inv = 1.f / l_run;
  #pragma unroll
  for (int dh = 0; dh < 2; dh++)
    #pragma unroll
    for (int r = 0; r < 16; r++) {
      int d = dh * 32 + (r & 3) + 8 * (r >> 2) + 4 * hb2;
      Ow[wave][l31 * 65 + d] = oaccT[dh][r] * inv;
    }
  asm volatile("s_waitcnt lgkmcnt(0)" ::: "memory");

  bf16* op = oT + (size_t)zb * o_bstride + (size_t)q0 * 256 + n * 64;
  #pragma unroll
  for (int q = 0; q < 32; q++) {
    float v = Ow[wave][q * 65 + lane];
    op[(size_t)q * 256 + lane] = __float2bfloat16(v);
  }
}

// proj GEMM on MFMA: out[b][m][l] = Pb[m][:]·o[:][l] + bproj[m] + x, f32 out.
__global__ __launch_bounds__(256) void gemm_proj_mfma(
    const bf16* __restrict__ Pb, const bf16* __restrict__ oT,
    const float* __restrict__ bproj, const float* __restrict__ x,
    float* __restrict__ out, int b_off, size_t o_bstride) {
  __shared__ bf16 As[128][40];
  __shared__ bf16 Bs[128][40];
  int zb = blockIdx.z, b = zb + b_off;
  int m0 = blockIdx.y * 128, l0 = blockIdx.x * 128;
  const bf16* ob = oT + (size_t)zb * o_bstride;
  int tid = threadIdx.x, lane = tid & 63, wave = tid >> 6;
  int l16 = lane & 15, quad = lane >> 4;
  int mi0 = (wave & 1) * 4, nj0 = (wave >> 1) * 4;
  float4v acc[4][4];
  #pragma unroll
  for (int i = 0; i < 4; i++)
    #pragma unroll
    for (int j = 0; j < 4; j++) acc[i][j] = (float4v){0.f, 0.f, 0.f, 0.f};

  for (int kc = 0; kc < 8; kc++) {
    __syncthreads();
    #pragma unroll
    for (int it = 0; it < 2; it++) {
      int s = it * 256 + tid;
      int mm = s >> 2, kk = (s & 3) * 8;
      *(short8*)&As[mm][kk] = *(const short8*)&Pb[(size_t)(m0 + mm) * 256 + kc * 32 + kk];
      *(short8*)&Bs[mm][kk] = *(const short8*)&ob[(size_t)(l0 + mm) * 256 + kc * 32 + kk];
    }
    __syncthreads();
    short8 af[4], bfr[4];
    #pragma unroll
    for (int i = 0; i < 4; i++) af[i]  = *(const short8*)&As[(mi0 + i) * 16 + l16][quad * 8];
    #pragma unroll
    for (int j = 0; j < 4; j++) bfr[j] = *(const short8*)&Bs[(nj0 + j) * 16 + l16][quad * 8];
    #pragma unroll
    for (int i = 0; i < 4; i++)
      #pragma unroll
      for (int j = 0; j < 4; j++)
        acc[i][j] = __builtin_amdgcn_mfma_f32_16x16x32_bf16(af[i], bfr[j], acc[i][j], 0, 0, 0);
  }

  #pragma unroll
  for (int i = 0; i < 4; i++) {
    #pragma unroll
    for (int r = 0; r < 4; r++) {
      int m = m0 + (mi0 + i) * 16 + quad * 4 + r;
      float bias = bproj[m];
      #pragma unroll
      for (int j = 0; j < 4; j++) {
        int l = l0 + (nj0 + j) * 16 + l16;
        size_t idx = (size_t)(b * 256 + m) * 1024 + l;
        out[idx] = acc[i][j][r] + bias + x[idx];
      }
    }
  }
}

extern "C" void kernel_launch(void* const* d_in, const int* in_sizes, int n_in,
                              void* d_out, int out_size, void* d_ws, size_t ws_size,
                              hipStream_t stream) {
  int ix = 0, iga = 1, ibe = 2, iwq = 3, ibq = 4, iwk = 5, ibk = 6,
      iwv = 7, ibv = 8, iwp = 9, ibp = 10;
  if (in_sizes[0] != 4194304) {
    if (in_sizes[10] == 4194304 && in_sizes[1] == 256) {
      ibe = 0; ibk = 1; ibp = 2; ibq = 3; ibv = 4; iga = 5;
      iwk = 6; iwp = 7; iwq = 8; iwv = 9; ix = 10;
    } else if (in_sizes[10] == 4194304 && in_sizes[1] == 65536) {
      ibp = 0; iwp = 1; ibv = 2; iwv = 3; ibk = 4; iwk = 5;
      ibq = 6; iwq = 7; ibe = 8; iga = 9; ix = 10;
    } else {
      for (int i = 0; i < 11; i++) if (in_sizes[i] == 4194304) ix = i;
    }
  }
  const float* x     = (const float*)d_in[ix];
  const float* gamma = (const float*)d_in[iga];
  const float* beta  = (const float*)d_in[ibe];
  const float* wq    = (const float*)d_in[iwq];
  const float* bq    = (const float*)d_in[ibq];
  const float* wk    = (const float*)d_in[iwk];
  const float* bk    = (const float*)d_in[ibk];
  const float* wv    = (const float*)d_in[iwv];
  const float* bv    = (const float*)d_in[ibv];
  const float* wproj = (const float*)d_in[iwp];
  const float* bproj = (const float*)d_in[ibp];
  float* out = (float*)d_out;

  const size_t QKV_B = (size_t)768 * 1024;
  const size_t O_B   = (size_t)256 * 1024;
  char* wsp = (char*)d_ws;
  float2* stats = (float2*)wsp;                        // 4 KB
  bf16* Wb = (bf16*)(wsp + 8192);                      // 384 KB
  bf16* Pb = (bf16*)(wsp + 8192 + 393216);             // 128 KB
  const size_t HT0 = 8192 + 393216 + 131072;
  size_t full_need = HT0 + (size_t)16 * O_B * 2 + (size_t)16 * QKV_B * 2; // ~34.1 MB

  stats_kernel<<<512, 256, 0, stream>>>(x, stats);
  wpack<<<1024, 256, 0, stream>>>(wq, wk, wv, wproj, Wb, Pb);

  if (ws_size >= full_need) {
    bf16* hT  = (bf16*)(wsp + HT0);                    // 8 MB; reused as oT
    bf16* qkv = (bf16*)(wsp + HT0 + 16 * O_B * 2);     // 24 MB
    bf16* oT  = hT;
    gnt_kernel   <<<dim3(16, 4, 16), 256, 0, stream>>>(x, gamma, beta, stats, hT, 0);
    gemm_qkv_mfma<<<dim3(8, 6, 16), 256, 0, stream>>>(hT, Wb, bq, bk, bv, qkv, QKV_B);
    attn_kernel  <<<dim3(8, 4, 16), 256, 0, stream>>>(qkv, oT, QKV_B, O_B);
    gemm_proj_mfma<<<dim3(8, 2, 16), 256, 0, stream>>>(Pb, oT, bproj, x, out, 0, O_B);
  } else {
    bf16* hT  = (bf16*)(wsp + HT0);
    bf16* qkv = (bf16*)(wsp + HT0 + O_B * 2);
    bf16* oT  = hT;
    for (int b = 0; b < 16; b++) {
      gnt_kernel   <<<dim3(16, 4, 1), 256, 0, stream>>>(x, gamma, beta, stats, hT, b);
      gemm_qkv_mfma<<<dim3(8, 6, 1), 256, 0, stream>>>(hT, Wb, bq, bk, bv, qkv, 0);
      attn_kernel  <<<dim3(8, 4, 1), 256, 0, stream>>>(qkv, oT, 0, 0);
      gemm_proj_mfma<<<dim3(8, 2, 1), 256, 0, stream>>>(Pb, oT, bproj, x, out, b, 0);
    }
  }
}

// Round 7
// 178.991 us; speedup vs baseline: 1.2158x; 1.0415x over previous
//
#include <hip/hip_runtime.h>
#include <hip/hip_bf16.h>
#include <stdint.h>

// Problem constants (B=16, C=256, NH=4, D=64, G=32, L=HW=1024)
// Round 23. R22 audit: 49.6us, VALUBusy 61% at 2 waves/SIMD -> ~560 VALU
// instrs per chunk vs ~120 hand-counted: __float2bfloat16 (~20 instrs each,
// x16) and exp2f OCML fixup (~10 each, x16) are the expansion. This round:
//  - P-pack via v_cvt_pk_bf16_f32 inline asm (16 lib cvts -> 8 instrs);
//    p is non-NaN by construction, RNE rounding matches.
//  - exp2 via __builtin_amdgcn_exp2f (raw v_exp_f32; args <= 8, HW
//    underflow OK) -> drops the OCML fixup path.
//  - max3-friendly max tree (clang fuses fmaxf pairs to v_max3_f32).
//  - 2-way KEY-SPLIT: wave owns 32 q x 512 keys; block = 2 q-tiles x 2
//    halves; grid 1024 (4 blocks/CU -> 4 waves/SIMD, 2x occupancy).
//    One-barrier LDS flash-merge (stride-68 f32, b128 writes 4-way=cheap,
//    reads 2-way=free). Same total L2 traffic.
// XCD swizzle kept (head h -> XCD h%8, bijective). Other kernels unchanged.

typedef __hip_bfloat16 bf16;
typedef __attribute__((ext_vector_type(8))) short short8;
typedef __attribute__((ext_vector_type(4))) float float4v;
typedef __attribute__((ext_vector_type(16))) float float16v;

#if __has_builtin(__builtin_amdgcn_exp2f)
#define EXP2F(x) __builtin_amdgcn_exp2f(x)
#else
#define EXP2F(x) exp2f(x)
#endif

__device__ __forceinline__ float max3f(float a, float b, float c) {
  return fmaxf(fmaxf(a, b), c);
}

// fragment-major index for Q^T/K^T per head: element (d, l) of Q[d][l]
__device__ __forceinline__ int qk_fidx(int d, int l) {
  return ((((l >> 5) * 4 + (d >> 4)) * 64 + ((d >> 3) & 1) * 32 + (l & 31)) << 3) + (d & 7);
}
// fragment-major index for V per head: element (d, l) of V[d][l]
__device__ __forceinline__ int v_fidx(int d, int l) {
  return (((((((l >> 5) * 2 + (d >> 5)) * 2 + ((l >> 4) & 1)) * 2 + ((l >> 3) & 1)) * 32) + (d & 31)) << 3) + (l & 7);
}

__global__ __launch_bounds__(256) void stats_kernel(const float* __restrict__ x,
    float2* __restrict__ stats) {
  int b = blockIdx.x >> 5, g = blockIdx.x & 31;
  const float* xp = x + (size_t)(b * 256 + g * 8) * 1024;
  float s = 0.f, ss = 0.f;
  for (int i = threadIdx.x; i < 8192; i += 256) {
    float v = xp[i]; s += v; ss += v * v;
  }
  #pragma unroll
  for (int o = 32; o; o >>= 1) { s += __shfl_down(s, o); ss += __shfl_down(ss, o); }
  __shared__ float red[2][4];
  int wid = threadIdx.x >> 6;
  if ((threadIdx.x & 63) == 0) { red[0][wid] = s; red[1][wid] = ss; }
  __syncthreads();
  if (threadIdx.x == 0) {
    s  = red[0][0] + red[0][1] + red[0][2] + red[0][3];
    ss = red[1][0] + red[1][1] + red[1][2] + red[1][3];
    float mean = s * (1.f / 8192.f);
    float var  = ss * (1.f / 8192.f) - mean * mean;
    stats[blockIdx.x] = make_float2(mean, rsqrtf(var + 1e-5f));
  }
}

// GN + transpose: hT[zb][l][c] = GN(x)[b][c][l], bf16.
__global__ __launch_bounds__(256) void gnt_kernel(const float* __restrict__ x,
    const float* __restrict__ gamma, const float* __restrict__ beta,
    const float2* __restrict__ stats, bf16* __restrict__ hT, int b_off) {
  __shared__ float T[64][65];
  int zb = blockIdx.z, b = zb + b_off;
  int c0 = blockIdx.y * 64, l0 = blockIdx.x * 64;
  const float* xb = x + (size_t)b * 262144;
  const float2* st = stats + b * 32;
  int tid = threadIdx.x;
  for (int i = tid; i < 4096; i += 256) {
    int cl = i >> 6, ll = i & 63;
    int c = c0 + cl;
    float2 s2 = st[c >> 3];
    T[cl][ll] = (xb[(size_t)c * 1024 + l0 + ll] - s2.x) * s2.y * gamma[c] + beta[c];
  }
  __syncthreads();
  bf16* hb = hT + (size_t)zb * 262144;
  for (int i = tid; i < 4096; i += 256) {
    int ll = i >> 6, cl = i & 63;
    hb[(size_t)(l0 + ll) * 256 + c0 + cl] = __float2bfloat16(T[cl][ll]);
  }
}

__global__ __launch_bounds__(256) void wpack(const float* __restrict__ wq,
    const float* __restrict__ wk, const float* __restrict__ wv,
    const float* __restrict__ wp, bf16* __restrict__ Wb, bf16* __restrict__ Pb) {
  int i = blockIdx.x * 256 + threadIdx.x;        // 262144 total
  if (i < 196608) {
    int r = i >> 8, c = i & 255;
    const float* src = (r < 256) ? wq : (r < 512) ? wk : wv;
    Wb[i] = __float2bfloat16(src[(r & 255) * 256 + c]);
  } else {
    int j = i - 196608;
    Pb[j] = __float2bfloat16(wp[j]);
  }
}

// qkv GEMM on MFMA: C[m][l] = Wb[m][:]·h[:][l] + bias. B^T = hT rows.
// Epilogue writes Q/K/V in attn FRAGMENT-MAJOR layouts (see qk_fidx/v_fidx).
// Q pre-scaled by 0.125*log2(e) (exp2-domain softmax).
__global__ __launch_bounds__(256) void gemm_qkv_mfma(
    const bf16* __restrict__ hT, const bf16* __restrict__ Wb,
    const float* __restrict__ bq, const float* __restrict__ bk,
    const float* __restrict__ bv,
    bf16* __restrict__ qkv, size_t qkv_bstride) {
  __shared__ bf16 As[128][40];
  __shared__ bf16 Bs[128][40];
  int zb = blockIdx.z;
  int m0 = blockIdx.y * 128, l0 = blockIdx.x * 128;
  const bf16* hb = hT + (size_t)zb * 262144;
  int tid = threadIdx.x, lane = tid & 63, wave = tid >> 6;
  int l16 = lane & 15, quad = lane >> 4;
  int mi0 = (wave & 1) * 4, nj0 = (wave >> 1) * 4;
  float4v acc[4][4];
  #pragma unroll
  for (int i = 0; i < 4; i++)
    #pragma unroll
    for (int j = 0; j < 4; j++) acc[i][j] = (float4v){0.f, 0.f, 0.f, 0.f};

  for (int kc = 0; kc < 8; kc++) {
    __syncthreads();
    #pragma unroll
    for (int it = 0; it < 2; it++) {
      int s = it * 256 + tid;
      int mm = s >> 2, kk = (s & 3) * 8;
      *(short8*)&As[mm][kk] = *(const short8*)&Wb[(size_t)(m0 + mm) * 256 + kc * 32 + kk];
      *(short8*)&Bs[mm][kk] = *(const short8*)&hb[(size_t)(l0 + mm) * 256 + kc * 32 + kk];
    }
    __syncthreads();
    short8 af[4], bfr[4];
    #pragma unroll
    for (int i = 0; i < 4; i++) af[i]  = *(const short8*)&As[(mi0 + i) * 16 + l16][quad * 8];
    #pragma unroll
    for (int j = 0; j < 4; j++) bfr[j] = *(const short8*)&Bs[(nj0 + j) * 16 + l16][quad * 8];
    #pragma unroll
    for (int i = 0; i < 4; i++)
      #pragma unroll
      for (int j = 0; j < 4; j++)
        acc[i][j] = __builtin_amdgcn_mfma_f32_16x16x32_bf16(af[i], bfr[j], acc[i][j], 0, 0, 0);
  }

  bf16* Cp = qkv + (size_t)zb * qkv_bstride;
  int sec = m0 >> 8;
  const float* bptr = (sec == 0) ? bq : (sec == 1) ? bk : bv;
  float osc = (sec == 0) ? 0.125f * 1.4426950408889634f : 1.0f;
  #pragma unroll
  for (int i = 0; i < 4; i++) {
    #pragma unroll
    for (int r = 0; r < 4; r++) {
      int m = m0 + (mi0 + i) * 16 + quad * 4 + r;
      int rr = m & 255;
      float bias = bptr[rr];
      int n = rr >> 6, d = rr & 63;
      if (sec <= 1) {
        bf16* Tp = Cp + sec * 262144 + n * 65536;       // frag-major Q/K
        #pragma unroll
        for (int j = 0; j < 4; j++) {
          int l = l0 + (nj0 + j) * 16 + l16;
          Tp[qk_fidx(d, l)] = __float2bfloat16((acc[i][j][r] + bias) * osc);
        }
      } else {
        bf16* Vf = Cp + 524288 + n * 65536;             // frag-major V
        #pragma unroll
        for (int j = 0; j < 4; j++) {
          int l = l0 + (nj0 + j) * 16 + l16;
          Vf[v_fidx(d, l)] = __float2bfloat16(acc[i][j][r] + bias);
        }
      }
    }
  }
}

// Flash MFMA attention, 2-way key-split: block = 2 q-tiles x 2 key-halves
// (4 waves); each wave owns 32 q over 512 keys. 32x32 MFMA, permlane P
// redistribution, frag-major coalesced loads, defer-max, cvt_pk P-pack,
// raw v_exp_f32. One barrier for the flash-merge. Grid 1024 blocks.
__global__ __launch_bounds__(256) void attn_kernel(
    const bf16* __restrict__ qkv, bf16* __restrict__ oT,
    size_t qkv_bstride, size_t o_bstride) {
  __shared__ __align__(16) float OB[2][2][2176];   // [half][qt][32q x 68]
  __shared__ float mL[2][2][32], lL[2][2][32];

  int zb, n, gg;
  {
    int f = blockIdx.x + (blockIdx.y << 4) + (blockIdx.z << 6);
    if (gridDim.z == 16) {
      // bijective XCD swizzle: wgid%8 == head%8 -> all 16 blocks of a head
      // on one XCD's L2
      int c = f & 7, r = f >> 3;
      int h = (r >> 4) * 8 + c;
      zb = h >> 2; n = h & 3; gg = r & 15;
    } else {
      zb = blockIdx.z; n = blockIdx.y; gg = blockIdx.x;
    }
  }
  const bf16* base = qkv + (size_t)zb * qkv_bstride;
  const bf16* Qf = base + n * 65536;              // frag-major, exp2-scaled
  const bf16* Kf = base + 262144 + n * 65536;     // frag-major
  const bf16* Vf = base + 524288 + n * 65536;     // frag-major
  int tid = threadIdx.x;
  int lane = tid & 63, wave = tid >> 6;
  int l31 = lane & 31, hb2 = lane >> 5;
  int qt = wave >> 1, half = wave & 1;
  int g = gg * 2 + qt;                            // q-tile 0..31
  int q0 = g << 5;

  // Q B-frags: coalesced 1KB loads
  short8 qb[4];
  #pragma unroll
  for (int ds = 0; ds < 4; ds++)
    qb[ds] = *(const short8*)&Qf[(((g * 4 + ds) << 6) + lane) << 3];

  float m_run = -1e30f, l_run = 0.f;
  float16v oaccT[2];
  #pragma unroll
  for (int dh = 0; dh < 2; dh++)
    #pragma unroll
    for (int r = 0; r < 16; r++) oaccT[dh][r] = 0.f;

  auto swp = [&](unsigned int a, unsigned int b, unsigned int& o0, unsigned int& o1) {
#if __has_builtin(__builtin_amdgcn_permlane32_swap)
    auto rr = __builtin_amdgcn_permlane32_swap((int)a, (int)b, false, false);
    o0 = (unsigned int)rr[0]; o1 = (unsigned int)rr[1];
#else
    unsigned int sa = (unsigned int)__shfl_xor((int)a, 32, 64);
    unsigned int sb = (unsigned int)__shfl_xor((int)b, 32, 64);
    o0 = hb2 ? sb : a;
    o1 = hb2 ? b : sa;
#endif
  };

  int k0 = half << 4;
  for (int kt = k0; kt < k0 + 16; kt++) {
    // K B-frags + V A-frags: coalesced 1KB loads
    short8 kf[4];
    #pragma unroll
    for (int ds = 0; ds < 4; ds++)
      kf[ds] = *(const short8*)&Kf[(((kt * 4 + ds) << 6) + lane) << 3];
    short8 vf[2][2];
    #pragma unroll
    for (int dh = 0; dh < 2; dh++)
      #pragma unroll
      for (int s = 0; s < 2; s++)
        vf[dh][s] = *(const short8*)&Vf[((((kt * 2 + dh) * 2 + s) << 6) + lane) << 3];

    // S[key 32][q 32] over d=64: 4 chained MFMAs
    float16v sacc;
    #pragma unroll
    for (int r = 0; r < 16; r++) sacc[r] = 0.f;
    #pragma unroll
    for (int ds = 0; ds < 4; ds++)
      sacc = __builtin_amdgcn_mfma_f32_32x32x16_bf16(kf[ds], qb[ds], sacc, 0, 0, 0);

    // chunk max: max3 tree + cross-half
    float a0 = max3f(sacc[0], sacc[1], sacc[2]);
    float a1 = max3f(sacc[3], sacc[4], sacc[5]);
    float a2 = max3f(sacc[6], sacc[7], sacc[8]);
    float a3 = max3f(sacc[9], sacc[10], sacc[11]);
    float a4 = max3f(sacc[12], sacc[13], sacc[14]);
    float cmax = fmaxf(max3f(a0, a1, a2), max3f(a3, a4, sacc[15]));
    cmax = fmaxf(cmax, __shfl_xor(cmax, 32, 64));

    // defer-max: rescale only when the bound would be exceeded (exp2 domain)
    if (__any(cmax > m_run + 8.f)) {
      float mnew = fmaxf(m_run, cmax);
      float alpha = EXP2F(m_run - mnew);
      #pragma unroll
      for (int dh = 0; dh < 2; dh++)
        #pragma unroll
        for (int r = 0; r < 16; r++) oaccT[dh][r] *= alpha;
      l_run *= alpha;
      m_run = mnew;
    }

    // p = exp2(s - m_run), bounded by 2^8 (raw v_exp_f32)
    float p[16];
    #pragma unroll
    for (int r = 0; r < 16; r++) p[r] = EXP2F(sacc[r] - m_run);
    float s0 = (p[0] + p[1]) + (p[2] + p[3]);
    float s1 = (p[4] + p[5]) + (p[6] + p[7]);
    float s2 = (p[8] + p[9]) + (p[10] + p[11]);
    float s3 = (p[12] + p[13]) + (p[14] + p[15]);
    float psum = (s0 + s1) + (s2 + s3);
    psum += __shfl_xor(psum, 32, 64);
    l_run += psum;

    // P -> PV B-frags: v_cvt_pk_bf16_f32 pairs, permlane32_swap halves
    unsigned int w[8];
    #pragma unroll
    for (int i = 0; i < 8; i++) {
      unsigned int pk;
      asm("v_cvt_pk_bf16_f32 %0, %1, %2" : "=v"(pk) : "v"(p[2 * i]), "v"(p[2 * i + 1]));
      w[i] = pk;
    }
    short8 pb[2];
    {
      unsigned int o0, o1, o2, o3;
      swp(w[0], w[2], o0, o2); swp(w[1], w[3], o1, o3);
      unsigned int* pw = (unsigned int*)&pb[0];
      pw[0] = o0; pw[1] = o1; pw[2] = o2; pw[3] = o3;
      swp(w[4], w[6], o0, o2); swp(w[5], w[7], o1, o3);
      pw = (unsigned int*)&pb[1];
      pw[0] = o0; pw[1] = o1; pw[2] = o2; pw[3] = o3;
    }

    // PV: O^T[d][q] += V^T * P, 2 d-halves x 2 key-slices
    #pragma unroll
    for (int dh = 0; dh < 2; dh++)
      #pragma unroll
      for (int s = 0; s < 2; s++)
        oaccT[dh] = __builtin_amdgcn_mfma_f32_32x32x16_bf16(vf[dh][s], pb[s], oaccT[dh], 0, 0, 0);
  }

  // flash-merge across the 2 key-halves of each q-tile (1 barrier)
  #pragma unroll
  for (int dh = 0; dh < 2; dh++)
    #pragma unroll
    for (int rq = 0; rq < 4; rq++) {
      float4v t = {oaccT[dh][4 * rq], oaccT[dh][4 * rq + 1],
                   oaccT[dh][4 * rq + 2], oaccT[dh][4 * rq + 3]};
      *(float4v*)&OB[half][qt][l31 * 68 + dh * 32 + 8 * rq + 4 * hb2] = t;
    }
  if (hb2 == 0) { mL[half][qt][l31] = m_run; lL[half][qt][l31] = l_run; }
  __syncthreads();

  bf16* op = oT + (size_t)zb * o_bstride + n * 64;
  const float* OA = OB[0][qt];
  const float* OBp = OB[1][qt];
  #pragma unroll
  for (int i = 0; i < 16; i++) {
    int q = (half << 4) + i;
    float mA = mL[0][qt][q], mB = mL[1][qt][q];
    float lA = lL[0][qt][q], lB = lL[1][qt][q];
    float ms = fmaxf(mA, mB);
    float eA = EXP2F(mA - ms), eB = EXP2F(mB - ms);
    float inv = 1.f / (lA * eA + lB * eB);
    float va = OA[q * 68 + lane], vb = OBp[q * 68 + lane];
    float o = (va * eA + vb * eB) * inv;
    op[(size_t)(q0 + q) * 256 + lane] = __float2bfloat16(o);
  }
}

// proj GEMM on MFMA: out[b][m][l] = Pb[m][:]·o[:][l] + bproj[m] + x, f32 out.
__global__ __launch_bounds__(256) void gemm_proj_mfma(
    const bf16* __restrict__ Pb, const bf16* __restrict__ oT,
    const float* __restrict__ bproj, const float* __restrict__ x,
    float* __restrict__ out, int b_off, size_t o_bstride) {
  __shared__ bf16 As[128][40];
  __shared__ bf16 Bs[128][40];
  int zb = blockIdx.z, b = zb + b_off;
  int m0 = blockIdx.y * 128, l0 = blockIdx.x * 128;
  const bf16* ob = oT + (size_t)zb * o_bstride;
  int tid = threadIdx.x, lane = tid & 63, wave = tid >> 6;
  int l16 = lane & 15, quad = lane >> 4;
  int mi0 = (wave & 1) * 4, nj0 = (wave >> 1) * 4;
  float4v acc[4][4];
  #pragma unroll
  for (int i = 0; i < 4; i++)
    #pragma unroll
    for (int j = 0; j < 4; j++) acc[i][j] = (float4v){0.f, 0.f, 0.f, 0.f};

  for (int kc = 0; kc < 8; kc++) {
    __syncthreads();
    #pragma unroll
    for (int it = 0; it < 2; it++) {
      int s = it * 256 + tid;
      int mm = s >> 2, kk = (s & 3) * 8;
      *(short8*)&As[mm][kk] = *(const short8*)&Pb[(size_t)(m0 + mm) * 256 + kc * 32 + kk];
      *(short8*)&Bs[mm][kk] = *(const short8*)&ob[(size_t)(l0 + mm) * 256 + kc * 32 + kk];
    }
    __syncthreads();
    short8 af[4], bfr[4];
    #pragma unroll
    for (int i = 0; i < 4; i++) af[i]  = *(const short8*)&As[(mi0 + i) * 16 + l16][quad * 8];
    #pragma unroll
    for (int j = 0; j < 4; j++) bfr[j] = *(const short8*)&Bs[(nj0 + j) * 16 + l16][quad * 8];
    #pragma unroll
    for (int i = 0; i < 4; i++)
      #pragma unroll
      for (int j = 0; j < 4; j++)
        acc[i][j] = __builtin_amdgcn_mfma_f32_16x16x32_bf16(af[i], bfr[j], acc[i][j], 0, 0, 0);
  }

  #pragma unroll
  for (int i = 0; i < 4; i++) {
    #pragma unroll
    for (int r = 0; r < 4; r++) {
      int m = m0 + (mi0 + i) * 16 + quad * 4 + r;
      float bias = bproj[m];
      #pragma unroll
      for (int j = 0; j < 4; j++) {
        int l = l0 + (nj0 + j) * 16 + l16;
        size_t idx = (size_t)(b * 256 + m) * 1024 + l;
        out[idx] = acc[i][j][r] + bias + x[idx];
      }
    }
  }
}

extern "C" void kernel_launch(void* const* d_in, const int* in_sizes, int n_in,
                              void* d_out, int out_size, void* d_ws, size_t ws_size,
                              hipStream_t stream) {
  int ix = 0, iga = 1, ibe = 2, iwq = 3, ibq = 4, iwk = 5, ibk = 6,
      iwv = 7, ibv = 8, iwp = 9, ibp = 10;
  if (in_sizes[0] != 4194304) {
    if (in_sizes[10] == 4194304 && in_sizes[1] == 256) {
      ibe = 0; ibk = 1; ibp = 2; ibq = 3; ibv = 4; iga = 5;
      iwk = 6; iwp = 7; iwq = 8; iwv = 9; ix = 10;
    } else if (in_sizes[10] == 4194304 && in_sizes[1] == 65536) {
      ibp = 0; iwp = 1; ibv = 2; iwv = 3; ibk = 4; iwk = 5;
      ibq = 6; iwq = 7; ibe = 8; iga = 9; ix = 10;
    } else {
      for (int i = 0; i < 11; i++) if (in_sizes[i] == 4194304) ix = i;
    }
  }
  const float* x     = (const float*)d_in[ix];
  const float* gamma = (const float*)d_in[iga];
  const float* beta  = (const float*)d_in[ibe];
  const float* wq    = (const float*)d_in[iwq];
  const float* bq    = (const float*)d_in[ibq];
  const float* wk    = (const float*)d_in[iwk];
  const float* bk    = (const float*)d_in[ibk];
  const float* wv    = (const float*)d_in[iwv];
  const float* bv    = (const float*)d_in[ibv];
  const float* wproj = (const float*)d_in[iwp];
  const float* bproj = (const float*)d_in[ibp];
  float* out = (float*)d_out;

  const size_t QKV_B = (size_t)768 * 1024;
  const size_t O_B   = (size_t)256 * 1024;
  char* wsp = (char*)d_ws;
  float2* stats = (float2*)wsp;                        // 4 KB
  bf16* Wb = (bf16*)(wsp + 8192);                      // 384 KB
  bf16* Pb = (bf16*)(wsp + 8192 + 393216);             // 128 KB
  const size_t HT0 = 8192 + 393216 + 131072;
  size_t full_need = HT0 + (size_t)16 * O_B * 2 + (size_t)16 * QKV_B * 2; // ~34.1 MB

  stats_kernel<<<512, 256, 0, stream>>>(x, stats);
  wpack<<<1024, 256, 0, stream>>>(wq, wk, wv, wproj, Wb, Pb);

  if (ws_size >= full_need) {
    bf16* hT  = (bf16*)(wsp + HT0);                    // 8 MB; reused as oT
    bf16* qkv = (bf16*)(wsp + HT0 + 16 * O_B * 2);     // 24 MB
    bf16* oT  = hT;
    gnt_kernel   <<<dim3(16, 4, 16), 256, 0, stream>>>(x, gamma, beta, stats, hT, 0);
    gemm_qkv_mfma<<<dim3(8, 6, 16), 256, 0, stream>>>(hT, Wb, bq, bk, bv, qkv, QKV_B);
    attn_kernel  <<<dim3(16, 4, 16), 256, 0, stream>>>(qkv, oT, QKV_B, O_B);
    gemm_proj_mfma<<<dim3(8, 2, 16), 256, 0, stream>>>(Pb, oT, bproj, x, out, 0, O_B);
  } else {
    bf16* hT  = (bf16*)(wsp + HT0);
    bf16* qkv = (bf16*)(wsp + HT0 + O_B * 2);
    bf16* oT  = hT;
    for (int b = 0; b < 16; b++) {
      gnt_kernel   <<<dim3(16, 4, 1), 256, 0, stream>>>(x, gamma, beta, stats, hT, b);
      gemm_qkv_mfma<<<dim3(8, 6, 1), 256, 0, stream>>>(hT, Wb, bq, bk, bv, qkv, 0);
      attn_kernel  <<<dim3(16, 4, 1), 256, 0, stream>>>(qkv, oT, 0, 0);
      gemm_proj_mfma<<<dim3(8, 2, 1), 256, 0, stream>>>(Pb, oT, bproj, x, out, b, 0);
    }
  }
}

// Round 8
// 174.784 us; speedup vs baseline: 1.2450x; 1.0241x over previous
//
#include <hip/hip_runtime.h>
#include <hip/hip_bf16.h>
#include <stdint.h>

// Problem constants (B=16, C=256, NH=4, D=64, G=32, L=HW=1024)
// Round 24. R23 post-mortem: attn ~42us (below the 43us harness fill in
// top-5). Budget: OTHER kernels+gaps = ~137us = 77% of the 179us total.
// This round restructures the pipeline (attn untouched):
//  - gnt DELETED: GroupNorm fused into gemm_qkv B-staging. Bs[l][c] =
//    bf16(x[c][l]*scale_c + shift_c) straight from x f32 (coalesced);
//    per-c scale/shift precomputed once into LDS. Bit-identical rounding
//    (one bf16 cvt, same as hT before). Saves hT write+read (~34MB) +
//    a whole kernel + launch.
//  - stats+wpack merged into one kernel (1536 blocks).
//  - gemm_qkv Q/K epilogue: 4 consecutive-d bf16 packed -> one 8B store
//    (stores x4 fewer). V unchanged (l-innermost, not packable).
// Pipeline: 6 launches -> 4. attn + proj unchanged from R23.

typedef __hip_bfloat16 bf16;
typedef __attribute__((ext_vector_type(8))) short short8;
typedef __attribute__((ext_vector_type(4))) float float4v;
typedef __attribute__((ext_vector_type(16))) float float16v;

#if __has_builtin(__builtin_amdgcn_exp2f)
#define EXP2F(x) __builtin_amdgcn_exp2f(x)
#else
#define EXP2F(x) exp2f(x)
#endif

__device__ __forceinline__ float max3f(float a, float b, float c) {
  return fmaxf(fmaxf(a, b), c);
}

// fragment-major index for Q^T/K^T per head: element (d, l) of Q[d][l]
__device__ __forceinline__ int qk_fidx(int d, int l) {
  return ((((l >> 5) * 4 + (d >> 4)) * 64 + ((d >> 3) & 1) * 32 + (l & 31)) << 3) + (d & 7);
}
// fragment-major index for V per head: element (d, l) of V[d][l]
__device__ __forceinline__ int v_fidx(int d, int l) {
  return (((((((l >> 5) * 2 + (d >> 5)) * 2 + ((l >> 4) & 1)) * 2 + ((l >> 3) & 1)) * 32) + (d & 31)) << 3) + (l & 7);
}

// stats (512 blocks) + weight pack (1024 blocks) in one launch
__global__ __launch_bounds__(256) void stats_wpack_kernel(
    const float* __restrict__ x, float2* __restrict__ stats,
    const float* __restrict__ wq, const float* __restrict__ wk,
    const float* __restrict__ wv, const float* __restrict__ wp,
    bf16* __restrict__ Wb, bf16* __restrict__ Pb) {
  if (blockIdx.x < 512) {
    int b = blockIdx.x >> 5, g = blockIdx.x & 31;
    const float* xp = x + (size_t)(b * 256 + g * 8) * 1024;
    float s = 0.f, ss = 0.f;
    for (int i = threadIdx.x; i < 8192; i += 256) {
      float v = xp[i]; s += v; ss += v * v;
    }
    #pragma unroll
    for (int o = 32; o; o >>= 1) { s += __shfl_down(s, o); ss += __shfl_down(ss, o); }
    __shared__ float red[2][4];
    int wid = threadIdx.x >> 6;
    if ((threadIdx.x & 63) == 0) { red[0][wid] = s; red[1][wid] = ss; }
    __syncthreads();
    if (threadIdx.x == 0) {
      s  = red[0][0] + red[0][1] + red[0][2] + red[0][3];
      ss = red[1][0] + red[1][1] + red[1][2] + red[1][3];
      float mean = s * (1.f / 8192.f);
      float var  = ss * (1.f / 8192.f) - mean * mean;
      stats[blockIdx.x] = make_float2(mean, rsqrtf(var + 1e-5f));
    }
  } else {
    int i = (blockIdx.x - 512) * 256 + threadIdx.x;   // 262144 total
    if (i < 196608) {
      int r = i >> 8, c = i & 255;
      const float* src = (r < 256) ? wq : (r < 512) ? wk : wv;
      Wb[i] = __float2bfloat16(src[(r & 255) * 256 + c]);
    } else {
      int j = i - 196608;
      Pb[j] = __float2bfloat16(wp[j]);
    }
  }
}

// Fused GN + qkv GEMM: C[m][l] = Wb[m][:]·GN(x)[b][:][l] + bias.
// B-tile staged straight from x f32 with inline GroupNorm (scale/shift per
// channel precomputed in LDS). Epilogue writes frag-major Q/K/V; Q/K packed
// 4-wide (consecutive d) into 8B stores. Q pre-scaled 0.125*log2e.
__global__ __launch_bounds__(256) void gemm_qkv_fused(
    const float* __restrict__ x, const float* __restrict__ gamma,
    const float* __restrict__ beta, const float2* __restrict__ stats,
    const bf16* __restrict__ Wb,
    const float* __restrict__ bq, const float* __restrict__ bk,
    const float* __restrict__ bv,
    bf16* __restrict__ qkv, size_t qkv_bstride, int b_off) {
  __shared__ bf16 As[128][40];
  __shared__ bf16 Bs[128][40];
  __shared__ float2 ssh[256];
  int zb = blockIdx.z, b = zb + b_off;
  int m0 = blockIdx.y * 128, l0 = blockIdx.x * 128;
  const float* xb = x + (size_t)b * 262144;
  int tid = threadIdx.x, lane = tid & 63, wave = tid >> 6;
  int l16 = lane & 15, quad = lane >> 4;
  int mi0 = (wave & 1) * 4, nj0 = (wave >> 1) * 4;

  {
    float2 st = stats[b * 32 + (tid >> 3)];
    float sc = st.y * gamma[tid];
    ssh[tid] = make_float2(sc, beta[tid] - st.x * sc);
  }

  float4v acc[4][4];
  #pragma unroll
  for (int i = 0; i < 4; i++)
    #pragma unroll
    for (int j = 0; j < 4; j++) acc[i][j] = (float4v){0.f, 0.f, 0.f, 0.f};

  for (int kc = 0; kc < 8; kc++) {
    __syncthreads();
    #pragma unroll
    for (int it = 0; it < 2; it++) {
      int s = it * 256 + tid;
      int mm = s >> 2, kk = (s & 3) * 8;
      *(short8*)&As[mm][kk] = *(const short8*)&Wb[(size_t)(m0 + mm) * 256 + kc * 32 + kk];
    }
    // B tile from x with inline GN: 32 c-rows x 128 l-cols, coalesced reads,
    // conflict-free transposed b16 writes (stride 80B -> 8 banks, acceptable)
    #pragma unroll
    for (int it = 0; it < 16; it++) {
      int i = it * 256 + tid;
      int cl = i >> 7, ll = i & 127;
      float2 sh = ssh[kc * 32 + cl];
      float v = xb[(size_t)(kc * 32 + cl) * 1024 + l0 + ll];
      Bs[ll][cl] = __float2bfloat16(v * sh.x + sh.y);
    }
    __syncthreads();
    short8 af[4], bfr[4];
    #pragma unroll
    for (int i = 0; i < 4; i++) af[i]  = *(const short8*)&As[(mi0 + i) * 16 + l16][quad * 8];
    #pragma unroll
    for (int j = 0; j < 4; j++) bfr[j] = *(const short8*)&Bs[(nj0 + j) * 16 + l16][quad * 8];
    #pragma unroll
    for (int i = 0; i < 4; i++)
      #pragma unroll
      for (int j = 0; j < 4; j++)
        acc[i][j] = __builtin_amdgcn_mfma_f32_16x16x32_bf16(af[i], bfr[j], acc[i][j], 0, 0, 0);
  }

  bf16* Cp = qkv + (size_t)zb * qkv_bstride;
  int sec = m0 >> 8;
  const float* bptr = (sec == 0) ? bq : (sec == 1) ? bk : bv;
  if (sec <= 1) {
    float osc = (sec == 0) ? 0.125f * 1.4426950408889634f : 1.0f;
    bf16* Tp = Cp + sec * 262144;
    #pragma unroll
    for (int i = 0; i < 4; i++) {
      int rrb = (m0 & 255) + (mi0 + i) * 16 + quad * 4;   // 4-aligned, no 8-cross
      int nh = rrb >> 6, d0 = rrb & 63;
      float b0 = bptr[rrb], b1 = bptr[rrb + 1], b2 = bptr[rrb + 2], b3 = bptr[rrb + 3];
      bf16* Tph = Tp + nh * 65536;
      #pragma unroll
      for (int j = 0; j < 4; j++) {
        int l = l0 + (nj0 + j) * 16 + l16;
        bf16 h0 = __float2bfloat16((acc[i][j][0] + b0) * osc);
        bf16 h1 = __float2bfloat16((acc[i][j][1] + b1) * osc);
        bf16 h2 = __float2bfloat16((acc[i][j][2] + b2) * osc);
        bf16 h3 = __float2bfloat16((acc[i][j][3] + b3) * osc);
        uint2 pk;
        pk.x = (unsigned int)*(unsigned short*)&h0 |
               ((unsigned int)*(unsigned short*)&h1 << 16);
        pk.y = (unsigned int)*(unsigned short*)&h2 |
               ((unsigned int)*(unsigned short*)&h3 << 16);
        *(uint2*)&Tph[qk_fidx(d0, l)] = pk;
      }
    }
  } else {
    bf16* Vfp = Cp + 524288;
    #pragma unroll
    for (int i = 0; i < 4; i++)
      #pragma unroll
      for (int r = 0; r < 4; r++) {
        int rr = (m0 & 255) + (mi0 + i) * 16 + quad * 4 + r;
        float bias = bptr[rr];
        int nh = rr >> 6, d = rr & 63;
        bf16* Vfh = Vfp + nh * 65536;
        #pragma unroll
        for (int j = 0; j < 4; j++) {
          int l = l0 + (nj0 + j) * 16 + l16;
          Vfh[v_fidx(d, l)] = __float2bfloat16(acc[i][j][r] + bias);
        }
      }
  }
}

// Flash MFMA attention, 2-way key-split (unchanged from R23).
__global__ __launch_bounds__(256) void attn_kernel(
    const bf16* __restrict__ qkv, bf16* __restrict__ oT,
    size_t qkv_bstride, size_t o_bstride) {
  __shared__ __align__(16) float OB[2][2][2176];   // [half][qt][32q x 68]
  __shared__ float mL[2][2][32], lL[2][2][32];

  int zb, n, gg;
  {
    int f = blockIdx.x + (blockIdx.y << 4) + (blockIdx.z << 6);
    if (gridDim.z == 16) {
      int c = f & 7, r = f >> 3;
      int h = (r >> 4) * 8 + c;
      zb = h >> 2; n = h & 3; gg = r & 15;
    } else {
      zb = blockIdx.z; n = blockIdx.y; gg = blockIdx.x;
    }
  }
  const bf16* base = qkv + (size_t)zb * qkv_bstride;
  const bf16* Qf = base + n * 65536;
  const bf16* Kf = base + 262144 + n * 65536;
  const bf16* Vf = base + 524288 + n * 65536;
  int tid = threadIdx.x;
  int lane = tid & 63, wave = tid >> 6;
  int l31 = lane & 31, hb2 = lane >> 5;
  int qt = wave >> 1, half = wave & 1;
  int g = gg * 2 + qt;
  int q0 = g << 5;

  short8 qb[4];
  #pragma unroll
  for (int ds = 0; ds < 4; ds++)
    qb[ds] = *(const short8*)&Qf[(((g * 4 + ds) << 6) + lane) << 3];

  float m_run = -1e30f, l_run = 0.f;
  float16v oaccT[2];
  #pragma unroll
  for (int dh = 0; dh < 2; dh++)
    #pragma unroll
    for (int r = 0; r < 16; r++) oaccT[dh][r] = 0.f;

  auto swp = [&](unsigned int a, unsigned int b, unsigned int& o0, unsigned int& o1) {
#if __has_builtin(__builtin_amdgcn_permlane32_swap)
    auto rr = __builtin_amdgcn_permlane32_swap((int)a, (int)b, false, false);
    o0 = (unsigned int)rr[0]; o1 = (unsigned int)rr[1];
#else
    unsigned int sa = (unsigned int)__shfl_xor((int)a, 32, 64);
    unsigned int sb = (unsigned int)__shfl_xor((int)b, 32, 64);
    o0 = hb2 ? sb : a;
    o1 = hb2 ? b : sa;
#endif
  };

  int k0 = half << 4;
  for (int kt = k0; kt < k0 + 16; kt++) {
    short8 kf[4];
    #pragma unroll
    for (int ds = 0; ds < 4; ds++)
      kf[ds] = *(const short8*)&Kf[(((kt * 4 + ds) << 6) + lane) << 3];
    short8 vf[2][2];
    #pragma unroll
    for (int dh = 0; dh < 2; dh++)
      #pragma unroll
      for (int s = 0; s < 2; s++)
        vf[dh][s] = *(const short8*)&Vf[((((kt * 2 + dh) * 2 + s) << 6) + lane) << 3];

    float16v sacc;
    #pragma unroll
    for (int r = 0; r < 16; r++) sacc[r] = 0.f;
    #pragma unroll
    for (int ds = 0; ds < 4; ds++)
      sacc = __builtin_amdgcn_mfma_f32_32x32x16_bf16(kf[ds], qb[ds], sacc, 0, 0, 0);

    float a0 = max3f(sacc[0], sacc[1], sacc[2]);
    float a1 = max3f(sacc[3], sacc[4], sacc[5]);
    float a2 = max3f(sacc[6], sacc[7], sacc[8]);
    float a3 = max3f(sacc[9], sacc[10], sacc[11]);
    float a4 = max3f(sacc[12], sacc[13], sacc[14]);
    float cmax = fmaxf(max3f(a0, a1, a2), max3f(a3, a4, sacc[15]));
    cmax = fmaxf(cmax, __shfl_xor(cmax, 32, 64));

    if (__any(cmax > m_run + 8.f)) {
      float mnew = fmaxf(m_run, cmax);
      float alpha = EXP2F(m_run - mnew);
      #pragma unroll
      for (int dh = 0; dh < 2; dh++)
        #pragma unroll
        for (int r = 0; r < 16; r++) oaccT[dh][r] *= alpha;
      l_run *= alpha;
      m_run = mnew;
    }

    float p[16];
    #pragma unroll
    for (int r = 0; r < 16; r++) p[r] = EXP2F(sacc[r] - m_run);
    float s0 = (p[0] + p[1]) + (p[2] + p[3]);
    float s1 = (p[4] + p[5]) + (p[6] + p[7]);
    float s2 = (p[8] + p[9]) + (p[10] + p[11]);
    float s3 = (p[12] + p[13]) + (p[14] + p[15]);
    float psum = (s0 + s1) + (s2 + s3);
    psum += __shfl_xor(psum, 32, 64);
    l_run += psum;

    unsigned int w[8];
    #pragma unroll
    for (int i = 0; i < 8; i++) {
      unsigned int pk;
      asm("v_cvt_pk_bf16_f32 %0, %1, %2" : "=v"(pk) : "v"(p[2 * i]), "v"(p[2 * i + 1]));
      w[i] = pk;
    }
    short8 pb[2];
    {
      unsigned int o0, o1, o2, o3;
      swp(w[0], w[2], o0, o2); swp(w[1], w[3], o1, o3);
      unsigned int* pw = (unsigned int*)&pb[0];
      pw[0] = o0; pw[1] = o1; pw[2] = o2; pw[3] = o3;
      swp(w[4], w[6], o0, o2); swp(w[5], w[7], o1, o3);
      pw = (unsigned int*)&pb[1];
      pw[0] = o0; pw[1] = o1; pw[2] = o2; pw[3] = o3;
    }

    #pragma unroll
    for (int dh = 0; dh < 2; dh++)
      #pragma unroll
      for (int s = 0; s < 2; s++)
        oaccT[dh] = __builtin_amdgcn_mfma_f32_32x32x16_bf16(vf[dh][s], pb[s], oaccT[dh], 0, 0, 0);
  }

  #pragma unroll
  for (int dh = 0; dh < 2; dh++)
    #pragma unroll
    for (int rq = 0; rq < 4; rq++) {
      float4v t = {oaccT[dh][4 * rq], oaccT[dh][4 * rq + 1],
                   oaccT[dh][4 * rq + 2], oaccT[dh][4 * rq + 3]};
      *(float4v*)&OB[half][qt][l31 * 68 + dh * 32 + 8 * rq + 4 * hb2] = t;
    }
  if (hb2 == 0) { mL[half][qt][l31] = m_run; lL[half][qt][l31] = l_run; }
  __syncthreads();

  bf16* op = oT + (size_t)zb * o_bstride + n * 64;
  const float* OA = OB[0][qt];
  const float* OBp = OB[1][qt];
  #pragma unroll
  for (int i = 0; i < 16; i++) {
    int q = (half << 4) + i;
    float mA = mL[0][qt][q], mB = mL[1][qt][q];
    float lA = lL[0][qt][q], lB = lL[1][qt][q];
    float ms = fmaxf(mA, mB);
    float eA = EXP2F(mA - ms), eB = EXP2F(mB - ms);
    float inv = 1.f / (lA * eA + lB * eB);
    float va = OA[q * 68 + lane], vb = OBp[q * 68 + lane];
    float o = (va * eA + vb * eB) * inv;
    op[(size_t)(q0 + q) * 256 + lane] = __float2bfloat16(o);
  }
}

// proj GEMM on MFMA: out[b][m][l] = Pb[m][:]·o[:][l] + bproj[m] + x, f32 out.
__global__ __launch_bounds__(256) void gemm_proj_mfma(
    const bf16* __restrict__ Pb, const bf16* __restrict__ oT,
    const float* __restrict__ bproj, const float* __restrict__ x,
    float* __restrict__ out, int b_off, size_t o_bstride) {
  __shared__ bf16 As[128][40];
  __shared__ bf16 Bs[128][40];
  int zb = blockIdx.z, b = zb + b_off;
  int m0 = blockIdx.y * 128, l0 = blockIdx.x * 128;
  const bf16* ob = oT + (size_t)zb * o_bstride;
  int tid = threadIdx.x, lane = tid & 63, wave = tid >> 6;
  int l16 = lane & 15, quad = lane >> 4;
  int mi0 = (wave & 1) * 4, nj0 = (wave >> 1) * 4;
  float4v acc[4][4];
  #pragma unroll
  for (int i = 0; i < 4; i++)
    #pragma unroll
    for (int j = 0; j < 4; j++) acc[i][j] = (float4v){0.f, 0.f, 0.f, 0.f};

  for (int kc = 0; kc < 8; kc++) {
    __syncthreads();
    #pragma unroll
    for (int it = 0; it < 2; it++) {
      int s = it * 256 + tid;
      int mm = s >> 2, kk = (s & 3) * 8;
      *(short8*)&As[mm][kk] = *(const short8*)&Pb[(size_t)(m0 + mm) * 256 + kc * 32 + kk];
      *(short8*)&Bs[mm][kk] = *(const short8*)&ob[(size_t)(l0 + mm) * 256 + kc * 32 + kk];
    }
    __syncthreads();
    short8 af[4], bfr[4];
    #pragma unroll
    for (int i = 0; i < 4; i++) af[i]  = *(const short8*)&As[(mi0 + i) * 16 + l16][quad * 8];
    #pragma unroll
    for (int j = 0; j < 4; j++) bfr[j] = *(const short8*)&Bs[(nj0 + j) * 16 + l16][quad * 8];
    #pragma unroll
    for (int i = 0; i < 4; i++)
      #pragma unroll
      for (int j = 0; j < 4; j++)
        acc[i][j] = __builtin_amdgcn_mfma_f32_16x16x32_bf16(af[i], bfr[j], acc[i][j], 0, 0, 0);
  }

  #pragma unroll
  for (int i = 0; i < 4; i++) {
    #pragma unroll
    for (int r = 0; r < 4; r++) {
      int m = m0 + (mi0 + i) * 16 + quad * 4 + r;
      float bias = bproj[m];
      #pragma unroll
      for (int j = 0; j < 4; j++) {
        int l = l0 + (nj0 + j) * 16 + l16;
        size_t idx = (size_t)(b * 256 + m) * 1024 + l;
        out[idx] = acc[i][j][r] + bias + x[idx];
      }
    }
  }
}

extern "C" void kernel_launch(void* const* d_in, const int* in_sizes, int n_in,
                              void* d_out, int out_size, void* d_ws, size_t ws_size,
                              hipStream_t stream) {
  int ix = 0, iga = 1, ibe = 2, iwq = 3, ibq = 4, iwk = 5, ibk = 6,
      iwv = 7, ibv = 8, iwp = 9, ibp = 10;
  if (in_sizes[0] != 4194304) {
    if (in_sizes[10] == 4194304 && in_sizes[1] == 256) {
      ibe = 0; ibk = 1; ibp = 2; ibq = 3; ibv = 4; iga = 5;
      iwk = 6; iwp = 7; iwq = 8; iwv = 9; ix = 10;
    } else if (in_sizes[10] == 4194304 && in_sizes[1] == 65536) {
      ibp = 0; iwp = 1; ibv = 2; iwv = 3; ibk = 4; iwk = 5;
      ibq = 6; iwq = 7; ibe = 8; iga = 9; ix = 10;
    } else {
      for (int i = 0; i < 11; i++) if (in_sizes[i] == 4194304) ix = i;
    }
  }
  const float* x     = (const float*)d_in[ix];
  const float* gamma = (const float*)d_in[iga];
  const float* beta  = (const float*)d_in[ibe];
  const float* wq    = (const float*)d_in[iwq];
  const float* bq    = (const float*)d_in[ibq];
  const float* wk    = (const float*)d_in[iwk];
  const float* bk    = (const float*)d_in[ibk];
  const float* wv    = (const float*)d_in[iwv];
  const float* bv    = (const float*)d_in[ibv];
  const float* wproj = (const float*)d_in[iwp];
  const float* bproj = (const float*)d_in[ibp];
  float* out = (float*)d_out;

  const size_t QKV_B = (size_t)768 * 1024;   // elements per batch
  const size_t O_B   = (size_t)256 * 1024;   // elements per batch
  char* wsp = (char*)d_ws;
  float2* stats = (float2*)wsp;                        // 4 KB
  bf16* Wb = (bf16*)(wsp + 8192);                      // 384 KB
  bf16* Pb = (bf16*)(wsp + 8192 + 393216);             // 128 KB
  const size_t OT0 = 8192 + 393216 + 131072;
  size_t full_need = OT0 + (size_t)16 * O_B * 2 + (size_t)16 * QKV_B * 2; // ~34.1 MB

  stats_wpack_kernel<<<1536, 256, 0, stream>>>(x, stats, wq, wk, wv, wproj, Wb, Pb);

  if (ws_size >= full_need) {
    bf16* oT  = (bf16*)(wsp + OT0);                    // 8 MB
    bf16* qkv = (bf16*)(wsp + OT0 + 16 * O_B * 2);     // 24 MB
    gemm_qkv_fused<<<dim3(8, 6, 16), 256, 0, stream>>>(x, gamma, beta, stats, Wb,
                                                       bq, bk, bv, qkv, QKV_B, 0);
    attn_kernel   <<<dim3(16, 4, 16), 256, 0, stream>>>(qkv, oT, QKV_B, O_B);
    gemm_proj_mfma<<<dim3(8, 2, 16), 256, 0, stream>>>(Pb, oT, bproj, x, out, 0, O_B);
  } else {
    bf16* oT  = (bf16*)(wsp + OT0);
    bf16* qkv = (bf16*)(wsp + OT0 + O_B * 2);
    for (int b = 0; b < 16; b++) {
      gemm_qkv_fused<<<dim3(8, 6, 1), 256, 0, stream>>>(x, gamma, beta, stats, Wb,
                                                        bq, bk, bv, qkv, 0, b);
      attn_kernel   <<<dim3(16, 4, 1), 256, 0, stream>>>(qkv, oT, 0, 0);
      gemm_proj_mfma<<<dim3(8, 2, 1), 256, 0, stream>>>(Pb, oT, bproj, x, out, b, 0);
    }
  }
}

// Round 9
// 153.050 us; speedup vs baseline: 1.4218x; 1.1420x over previous
//
#include <hip/hip_runtime.h>
#include <hip/hip_bf16.h>
#include <stdint.h>

// Problem constants (B=16, C=256, NH=4, D=64, G=32, L=HW=1024)
// Round 25. R24 falsifier fired (gnt deletion = only 4us) -> per plan, fuse
// attn+proj. Block = (batch, 32 q) x ALL 4 heads (8 waves: 4 heads x 2
// key-halves, R23 attn body unchanged). After the flash-merge, the block
// holds O[32 l][256 e] in LDS (bf16, row-pad 264) -> proj = 16 chained
// 32x32 MFMAs per wave (wave w owns out rows 32w..32w+31), A = O_lds row
// b128 reads, B = PbF (wproj re-packed frag-major in stats_wpack, 1KB
// coalesced). oT buffer + proj kernel + launch DELETED. Merge math
// identical to R23/R24 (same formula, same bf16 rounding points).
// LDS 52.7KB -> 3 blocks/CU = 24 waves/CU (6/SIMD vs R23's 4).
// Pipeline: 3 launches. stats_wpack/gemm_qkv_fused otherwise unchanged.

typedef __hip_bfloat16 bf16;
typedef __attribute__((ext_vector_type(8))) short short8;
typedef __attribute__((ext_vector_type(4))) float float4v;
typedef __attribute__((ext_vector_type(16))) float float16v;

#if __has_builtin(__builtin_amdgcn_exp2f)
#define EXP2F(x) __builtin_amdgcn_exp2f(x)
#else
#define EXP2F(x) exp2f(x)
#endif

__device__ __forceinline__ float max3f(float a, float b, float c) {
  return fmaxf(fmaxf(a, b), c);
}

// fragment-major index for Q^T/K^T per head: element (d, l) of Q[d][l]
__device__ __forceinline__ int qk_fidx(int d, int l) {
  return ((((l >> 5) * 4 + (d >> 4)) * 64 + ((d >> 3) & 1) * 32 + (l & 31)) << 3) + (d & 7);
}
// fragment-major index for V per head: element (d, l) of V[d][l]
__device__ __forceinline__ int v_fidx(int d, int l) {
  return (((((((l >> 5) * 2 + (d >> 5)) * 2 + ((l >> 4) & 1)) * 2 + ((l >> 3) & 1)) * 32) + (d & 31)) << 3) + (l & 7);
}

// stats (512 blocks) + weight pack (1024 blocks) in one launch.
// Pb is packed FRAG-MAJOR for the fused proj B-operand:
// PbF[((w*16+kk)*64+lane)*8+j] = wproj[(w*32+(lane&31))*256 + kk*16+(lane>>5)*8+j]
__global__ __launch_bounds__(256) void stats_wpack_kernel(
    const float* __restrict__ x, float2* __restrict__ stats,
    const float* __restrict__ wq, const float* __restrict__ wk,
    const float* __restrict__ wv, const float* __restrict__ wp,
    bf16* __restrict__ Wb, bf16* __restrict__ Pb) {
  if (blockIdx.x < 512) {
    int b = blockIdx.x >> 5, g = blockIdx.x & 31;
    const float* xp = x + (size_t)(b * 256 + g * 8) * 1024;
    float s = 0.f, ss = 0.f;
    for (int i = threadIdx.x; i < 8192; i += 256) {
      float v = xp[i]; s += v; ss += v * v;
    }
    #pragma unroll
    for (int o = 32; o; o >>= 1) { s += __shfl_down(s, o); ss += __shfl_down(ss, o); }
    __shared__ float red[2][4];
    int wid = threadIdx.x >> 6;
    if ((threadIdx.x & 63) == 0) { red[0][wid] = s; red[1][wid] = ss; }
    __syncthreads();
    if (threadIdx.x == 0) {
      s  = red[0][0] + red[0][1] + red[0][2] + red[0][3];
      ss = red[1][0] + red[1][1] + red[1][2] + red[1][3];
      float mean = s * (1.f / 8192.f);
      float var  = ss * (1.f / 8192.f) - mean * mean;
      stats[blockIdx.x] = make_float2(mean, rsqrtf(var + 1e-5f));
    }
  } else {
    int i = (blockIdx.x - 512) * 256 + threadIdx.x;   // 262144 total
    if (i < 196608) {
      int r = i >> 8, c = i & 255;
      const float* src = (r < 256) ? wq : (r < 512) ? wk : wv;
      Wb[i] = __float2bfloat16(src[(r & 255) * 256 + c]);
    } else {
      int j2 = i - 196608;                            // 0..65535
      int jj = j2 & 7, lane2 = (j2 >> 3) & 63;
      int kk2 = (j2 >> 9) & 15, w2 = j2 >> 13;
      int m = w2 * 32 + (lane2 & 31);
      int e = kk2 * 16 + (lane2 >> 5) * 8 + jj;
      Pb[j2] = __float2bfloat16(wp[m * 256 + e]);
    }
  }
}

// Fused GN + qkv GEMM (unchanged from R24).
__global__ __launch_bounds__(256) void gemm_qkv_fused(
    const float* __restrict__ x, const float* __restrict__ gamma,
    const float* __restrict__ beta, const float2* __restrict__ stats,
    const bf16* __restrict__ Wb,
    const float* __restrict__ bq, const float* __restrict__ bk,
    const float* __restrict__ bv,
    bf16* __restrict__ qkv, size_t qkv_bstride, int b_off) {
  __shared__ bf16 As[128][40];
  __shared__ bf16 Bs[128][40];
  __shared__ float2 ssh[256];
  int zb = blockIdx.z, b = zb + b_off;
  int m0 = blockIdx.y * 128, l0 = blockIdx.x * 128;
  const float* xb = x + (size_t)b * 262144;
  int tid = threadIdx.x, lane = tid & 63, wave = tid >> 6;
  int l16 = lane & 15, quad = lane >> 4;
  int mi0 = (wave & 1) * 4, nj0 = (wave >> 1) * 4;

  {
    float2 st = stats[b * 32 + (tid >> 3)];
    float sc = st.y * gamma[tid];
    ssh[tid] = make_float2(sc, beta[tid] - st.x * sc);
  }

  float4v acc[4][4];
  #pragma unroll
  for (int i = 0; i < 4; i++)
    #pragma unroll
    for (int j = 0; j < 4; j++) acc[i][j] = (float4v){0.f, 0.f, 0.f, 0.f};

  for (int kc = 0; kc < 8; kc++) {
    __syncthreads();
    #pragma unroll
    for (int it = 0; it < 2; it++) {
      int s = it * 256 + tid;
      int mm = s >> 2, kk = (s & 3) * 8;
      *(short8*)&As[mm][kk] = *(const short8*)&Wb[(size_t)(m0 + mm) * 256 + kc * 32 + kk];
    }
    #pragma unroll
    for (int it = 0; it < 16; it++) {
      int i = it * 256 + tid;
      int cl = i >> 7, ll = i & 127;
      float2 sh = ssh[kc * 32 + cl];
      float v = xb[(size_t)(kc * 32 + cl) * 1024 + l0 + ll];
      Bs[ll][cl] = __float2bfloat16(v * sh.x + sh.y);
    }
    __syncthreads();
    short8 af[4], bfr[4];
    #pragma unroll
    for (int i = 0; i < 4; i++) af[i]  = *(const short8*)&As[(mi0 + i) * 16 + l16][quad * 8];
    #pragma unroll
    for (int j = 0; j < 4; j++) bfr[j] = *(const short8*)&Bs[(nj0 + j) * 16 + l16][quad * 8];
    #pragma unroll
    for (int i = 0; i < 4; i++)
      #pragma unroll
      for (int j = 0; j < 4; j++)
        acc[i][j] = __builtin_amdgcn_mfma_f32_16x16x32_bf16(af[i], bfr[j], acc[i][j], 0, 0, 0);
  }

  bf16* Cp = qkv + (size_t)zb * qkv_bstride;
  int sec = m0 >> 8;
  const float* bptr = (sec == 0) ? bq : (sec == 1) ? bk : bv;
  if (sec <= 1) {
    float osc = (sec == 0) ? 0.125f * 1.4426950408889634f : 1.0f;
    bf16* Tp = Cp + sec * 262144;
    #pragma unroll
    for (int i = 0; i < 4; i++) {
      int rrb = (m0 & 255) + (mi0 + i) * 16 + quad * 4;
      int nh = rrb >> 6, d0 = rrb & 63;
      float b0 = bptr[rrb], b1 = bptr[rrb + 1], b2 = bptr[rrb + 2], b3 = bptr[rrb + 3];
      bf16* Tph = Tp + nh * 65536;
      #pragma unroll
      for (int j = 0; j < 4; j++) {
        int l = l0 + (nj0 + j) * 16 + l16;
        bf16 h0 = __float2bfloat16((acc[i][j][0] + b0) * osc);
        bf16 h1 = __float2bfloat16((acc[i][j][1] + b1) * osc);
        bf16 h2 = __float2bfloat16((acc[i][j][2] + b2) * osc);
        bf16 h3 = __float2bfloat16((acc[i][j][3] + b3) * osc);
        uint2 pk;
        pk.x = (unsigned int)*(unsigned short*)&h0 |
               ((unsigned int)*(unsigned short*)&h1 << 16);
        pk.y = (unsigned int)*(unsigned short*)&h2 |
               ((unsigned int)*(unsigned short*)&h3 << 16);
        *(uint2*)&Tph[qk_fidx(d0, l)] = pk;
      }
    }
  } else {
    bf16* Vfp = Cp + 524288;
    #pragma unroll
    for (int i = 0; i < 4; i++)
      #pragma unroll
      for (int r = 0; r < 4; r++) {
        int rr = (m0 & 255) + (mi0 + i) * 16 + quad * 4 + r;
        float bias = bptr[rr];
        int nh = rr >> 6, d = rr & 63;
        bf16* Vfh = Vfp + nh * 65536;
        #pragma unroll
        for (int j = 0; j < 4; j++) {
          int l = l0 + (nj0 + j) * 16 + l16;
          Vfh[v_fidx(d, l)] = __float2bfloat16(acc[i][j][r] + bias);
        }
      }
  }
}

// Fused flash attention + output projection + residual.
// Block = (batch, 32 q-rows); 8 waves = 4 heads x 2 key-halves.
// attn body identical to R23. After merge, O[32 l][256 e] lives in LDS
// (bf16, row stride 264); proj: wave w -> out rows 32w..32w+31 via 16
// chained 32x32 MFMAs (A = O_lds rows, B = PbF coalesced); + bias + x.
__global__ __launch_bounds__(512) void attn_proj_kernel(
    const bf16* __restrict__ qkv, const bf16* __restrict__ PbF,
    const float* __restrict__ bproj, const float* __restrict__ x,
    float* __restrict__ out, size_t qkv_bstride, int b_off) {
  __shared__ __align__(16) char lds[52736];
  float* OB   = (float*)lds;              // [4 heads][32 q][68] f32 = 34816 B
  float* mL   = (float*)(lds + 34816);    // [4][32]
  float* lL   = (float*)(lds + 35328);    // [4][32]
  bf16*  O_lds = (bf16*)(lds + 35840);    // [32 q][264 e] = 16896 B

  int b, qg;
  {
    int f = blockIdx.x;
    if (gridDim.x == 512) {               // XCD swizzle: wgid%8 == b%8
      int c = f & 7, t = f >> 3;
      b = ((t & 1) << 3) + c; qg = t >> 1;
    } else {
      b = b_off; qg = f;
    }
  }
  const bf16* base = qkv + (size_t)(gridDim.x == 512 ? b : 0) * qkv_bstride;
  int tid = threadIdx.x;
  int lane = tid & 63, wave = tid >> 6;
  int l31 = lane & 31, hb2 = lane >> 5;
  int n = wave & 3, half = wave >> 2;
  const bf16* Qf = base + n * 65536;
  const bf16* Kf = base + 262144 + n * 65536;
  const bf16* Vf = base + 524288 + n * 65536;

  // Q B-frags: coalesced 1KB loads
  short8 qb[4];
  #pragma unroll
  for (int ds = 0; ds < 4; ds++)
    qb[ds] = *(const short8*)&Qf[(((qg * 4 + ds) << 6) + lane) << 3];

  float m_run = -1e30f, l_run = 0.f;
  float16v oaccT[2];
  #pragma unroll
  for (int dh = 0; dh < 2; dh++)
    #pragma unroll
    for (int r = 0; r < 16; r++) oaccT[dh][r] = 0.f;

  auto swp = [&](unsigned int a, unsigned int bb, unsigned int& o0, unsigned int& o1) {
#if __has_builtin(__builtin_amdgcn_permlane32_swap)
    auto rr = __builtin_amdgcn_permlane32_swap((int)a, (int)bb, false, false);
    o0 = (unsigned int)rr[0]; o1 = (unsigned int)rr[1];
#else
    unsigned int sa = (unsigned int)__shfl_xor((int)a, 32, 64);
    unsigned int sb = (unsigned int)__shfl_xor((int)bb, 32, 64);
    o0 = hb2 ? sb : a;
    o1 = hb2 ? bb : sa;
#endif
  };

  int k0 = half << 4;
  for (int kt = k0; kt < k0 + 16; kt++) {
    short8 kf[4];
    #pragma unroll
    for (int ds = 0; ds < 4; ds++)
      kf[ds] = *(const short8*)&Kf[(((kt * 4 + ds) << 6) + lane) << 3];
    short8 vf[2][2];
    #pragma unroll
    for (int dh = 0; dh < 2; dh++)
      #pragma unroll
      for (int s = 0; s < 2; s++)
        vf[dh][s] = *(const short8*)&Vf[((((kt * 2 + dh) * 2 + s) << 6) + lane) << 3];

    float16v sacc;
    #pragma unroll
    for (int r = 0; r < 16; r++) sacc[r] = 0.f;
    #pragma unroll
    for (int ds = 0; ds < 4; ds++)
      sacc = __builtin_amdgcn_mfma_f32_32x32x16_bf16(kf[ds], qb[ds], sacc, 0, 0, 0);

    float a0 = max3f(sacc[0], sacc[1], sacc[2]);
    float a1 = max3f(sacc[3], sacc[4], sacc[5]);
    float a2 = max3f(sacc[6], sacc[7], sacc[8]);
    float a3 = max3f(sacc[9], sacc[10], sacc[11]);
    float a4 = max3f(sacc[12], sacc[13], sacc[14]);
    float cmax = fmaxf(max3f(a0, a1, a2), max3f(a3, a4, sacc[15]));
    cmax = fmaxf(cmax, __shfl_xor(cmax, 32, 64));

    if (__any(cmax > m_run + 8.f)) {
      float mnew = fmaxf(m_run, cmax);
      float alpha = EXP2F(m_run - mnew);
      #pragma unroll
      for (int dh = 0; dh < 2; dh++)
        #pragma unroll
        for (int r = 0; r < 16; r++) oaccT[dh][r] *= alpha;
      l_run *= alpha;
      m_run = mnew;
    }

    float p[16];
    #pragma unroll
    for (int r = 0; r < 16; r++) p[r] = EXP2F(sacc[r] - m_run);
    float s0 = (p[0] + p[1]) + (p[2] + p[3]);
    float s1 = (p[4] + p[5]) + (p[6] + p[7]);
    float s2 = (p[8] + p[9]) + (p[10] + p[11]);
    float s3 = (p[12] + p[13]) + (p[14] + p[15]);
    float psum = (s0 + s1) + (s2 + s3);
    psum += __shfl_xor(psum, 32, 64);
    l_run += psum;

    unsigned int w[8];
    #pragma unroll
    for (int i = 0; i < 8; i++) {
      unsigned int pk;
      asm("v_cvt_pk_bf16_f32 %0, %1, %2" : "=v"(pk) : "v"(p[2 * i]), "v"(p[2 * i + 1]));
      w[i] = pk;
    }
    short8 pb[2];
    {
      unsigned int o0, o1, o2, o3;
      swp(w[0], w[2], o0, o2); swp(w[1], w[3], o1, o3);
      unsigned int* pw = (unsigned int*)&pb[0];
      pw[0] = o0; pw[1] = o1; pw[2] = o2; pw[3] = o3;
      swp(w[4], w[6], o0, o2); swp(w[5], w[7], o1, o3);
      pw = (unsigned int*)&pb[1];
      pw[0] = o0; pw[1] = o1; pw[2] = o2; pw[3] = o3;
    }

    #pragma unroll
    for (int dh = 0; dh < 2; dh++)
      #pragma unroll
      for (int s = 0; s < 2; s++)
        oaccT[dh] = __builtin_amdgcn_mfma_f32_32x32x16_bf16(vf[dh][s], pb[s], oaccT[dh], 0, 0, 0);
  }

  // half-1 waves dump partials; half-0 waves merge -> O_lds (bf16)
  if (half == 1) {
    float* OBn = OB + n * 2176;
    #pragma unroll
    for (int dh = 0; dh < 2; dh++)
      #pragma unroll
      for (int rq = 0; rq < 4; rq++) {
        float4v t = {oaccT[dh][4 * rq], oaccT[dh][4 * rq + 1],
                     oaccT[dh][4 * rq + 2], oaccT[dh][4 * rq + 3]};
        *(float4v*)&OBn[l31 * 68 + dh * 32 + 8 * rq + 4 * hb2] = t;
      }
    if (hb2 == 0) { mL[n * 32 + l31] = m_run; lL[n * 32 + l31] = l_run; }
  }
  __syncthreads();
  if (half == 0) {
    float mB = mL[n * 32 + l31], lB = lL[n * 32 + l31];
    float ms = fmaxf(m_run, mB);
    float eA = EXP2F(m_run - ms), eB = EXP2F(mB - ms);
    float inv = 1.f / (l_run * eA + lB * eB);
    eA *= inv; eB *= inv;
    const float* OBn = OB + n * 2176 + l31 * 68;
    bf16* orow = O_lds + l31 * 264 + n * 64;
    #pragma unroll
    for (int dh = 0; dh < 2; dh++)
      #pragma unroll
      for (int r = 0; r < 16; r++) {
        int d = dh * 32 + (r & 3) + 8 * (r >> 2) + 4 * hb2;
        orow[d] = __float2bfloat16(oaccT[dh][r] * eA + OBn[d] * eB);
      }
  }
  __syncthreads();

  // proj: wave w -> out rows m = 32w .. 32w+31 for l = qg*32 .. +31
  float16v pacc;
  #pragma unroll
  for (int r = 0; r < 16; r++) pacc[r] = 0.f;
  #pragma unroll
  for (int kk = 0; kk < 16; kk++) {
    short8 a = *(const short8*)&O_lds[l31 * 264 + kk * 16 + hb2 * 8];
    short8 bb = *(const short8*)&PbF[(((wave * 16 + kk) << 6) + lane) << 3];
    pacc = __builtin_amdgcn_mfma_f32_32x32x16_bf16(a, bb, pacc, 0, 0, 0);
  }
  int m = (wave << 5) + l31;
  float bias = bproj[m];
  const float* xr = x + (((size_t)(b * 256 + m)) << 10) + (qg << 5);
  float* orw = out + (((size_t)(b * 256 + m)) << 10) + (qg << 5);
  #pragma unroll
  for (int r = 0; r < 16; r++) {
    int ll = (r & 3) + 8 * (r >> 2) + 4 * hb2;
    orw[ll] = pacc[r] + bias + xr[ll];
  }
}

extern "C" void kernel_launch(void* const* d_in, const int* in_sizes, int n_in,
                              void* d_out, int out_size, void* d_ws, size_t ws_size,
                              hipStream_t stream) {
  int ix = 0, iga = 1, ibe = 2, iwq = 3, ibq = 4, iwk = 5, ibk = 6,
      iwv = 7, ibv = 8, iwp = 9, ibp = 10;
  if (in_sizes[0] != 4194304) {
    if (in_sizes[10] == 4194304 && in_sizes[1] == 256) {
      ibe = 0; ibk = 1; ibp = 2; ibq = 3; ibv = 4; iga = 5;
      iwk = 6; iwp = 7; iwq = 8; iwv = 9; ix = 10;
    } else if (in_sizes[10] == 4194304 && in_sizes[1] == 65536) {
      ibp = 0; iwp = 1; ibv = 2; iwv = 3; ibk = 4; iwk = 5;
      ibq = 6; iwq = 7; ibe = 8; iga = 9; ix = 10;
    } else {
      for (int i = 0; i < 11; i++) if (in_sizes[i] == 4194304) ix = i;
    }
  }
  const float* x     = (const float*)d_in[ix];
  const float* gamma = (const float*)d_in[iga];
  const float* beta  = (const float*)d_in[ibe];
  const float* wq    = (const float*)d_in[iwq];
  const float* bq    = (const float*)d_in[ibq];
  const float* wk    = (const float*)d_in[iwk];
  const float* bk    = (const float*)d_in[ibk];
  const float* wv    = (const float*)d_in[iwv];
  const float* bv    = (const float*)d_in[ibv];
  const float* wproj = (const float*)d_in[iwp];
  const float* bproj = (const float*)d_in[ibp];
  float* out = (float*)d_out;

  const size_t QKV_B = (size_t)768 * 1024;   // elements per batch
  char* wsp = (char*)d_ws;
  float2* stats = (float2*)wsp;                        // 4 KB
  bf16* Wb = (bf16*)(wsp + 8192);                      // 384 KB
  bf16* Pb = (bf16*)(wsp + 8192 + 393216);             // 128 KB (frag-major)
  const size_t QKV0 = 8192 + 393216 + 131072;
  size_t full_need = QKV0 + (size_t)16 * QKV_B * 2;    // ~24.7 MB

  stats_wpack_kernel<<<1536, 256, 0, stream>>>(x, stats, wq, wk, wv, wproj, Wb, Pb);

  if (ws_size >= full_need) {
    bf16* qkv = (bf16*)(wsp + QKV0);                   // 24 MB
    gemm_qkv_fused<<<dim3(8, 6, 16), 256, 0, stream>>>(x, gamma, beta, stats, Wb,
                                                       bq, bk, bv, qkv, QKV_B, 0);
    attn_proj_kernel<<<512, 512, 0, stream>>>(qkv, Pb, bproj, x, out, QKV_B, 0);
  } else {
    bf16* qkv = (bf16*)(wsp + QKV0);
    for (int b = 0; b < 16; b++) {
      gemm_qkv_fused<<<dim3(8, 6, 1), 256, 0, stream>>>(x, gamma, beta, stats, Wb,
                                                        bq, bk, bv, qkv, 0, b);
      attn_proj_kernel<<<32, 512, 0, stream>>>(qkv, Pb, bproj, x, out, 0, b);
    }
  }
}

// Round 10
// 147.137 us; speedup vs baseline: 1.4790x; 1.0402x over previous
//
#include <hip/hip_runtime.h>
#include <hip/hip_bf16.h>
#include <stdint.h>

// Problem constants (B=16, C=256, NH=4, D=64, G=32, L=HW=1024)
// Round 26. R25 fused attn+proj (174.8->153.1us). Remaining addressable
// cost: instruction bloat (R22's lesson applied to the REST of the
// pipeline). gemm_qkv B-staging: 16 lib bf16-cvts (~15-20 instr each) +
// 8-way-conflicted b16 LDS writes + 16 scalar loads per thread per kc ->
// rewritten as 4 coalesced f32 loads + 2 v_cvt_pk_bf16_f32 + 1 b64 write.
// Q/K epilogue 4 lib cvts -> 2 cvt_pk; V epilogue 64 lib cvts -> 32
// cvt_pk+shift. attn_proj merge: 32 lib cvts -> 16 cvt_pk + b32 writes;
// final out: 16 scalar f32 -> 8 float2 stores. stats: float4 loads.
// All cvt_pk swaps RNE-for-RNE on finite values (bit-identical; attn has
// used cvt_pk since R23). Structure/grids unchanged from R25.

typedef __hip_bfloat16 bf16;
typedef __attribute__((ext_vector_type(8))) short short8;
typedef __attribute__((ext_vector_type(4))) float float4v;
typedef __attribute__((ext_vector_type(16))) float float16v;

#if __has_builtin(__builtin_amdgcn_exp2f)
#define EXP2F(x) __builtin_amdgcn_exp2f(x)
#else
#define EXP2F(x) exp2f(x)
#endif

__device__ __forceinline__ float max3f(float a, float b, float c) {
  return fmaxf(fmaxf(a, b), c);
}
__device__ __forceinline__ unsigned int cvtpk(float lo, float hi) {
  unsigned int pk;
  asm("v_cvt_pk_bf16_f32 %0, %1, %2" : "=v"(pk) : "v"(lo), "v"(hi));
  return pk;
}

// fragment-major index for Q^T/K^T per head: element (d, l) of Q[d][l]
__device__ __forceinline__ int qk_fidx(int d, int l) {
  return ((((l >> 5) * 4 + (d >> 4)) * 64 + ((d >> 3) & 1) * 32 + (l & 31)) << 3) + (d & 7);
}
// fragment-major index for V per head: element (d, l) of V[d][l]
__device__ __forceinline__ int v_fidx(int d, int l) {
  return (((((((l >> 5) * 2 + (d >> 5)) * 2 + ((l >> 4) & 1)) * 2 + ((l >> 3) & 1)) * 32) + (d & 31)) << 3) + (l & 7);
}

// stats (512 blocks) + weight pack (1024 blocks) in one launch.
__global__ __launch_bounds__(256) void stats_wpack_kernel(
    const float* __restrict__ x, float2* __restrict__ stats,
    const float* __restrict__ wq, const float* __restrict__ wk,
    const float* __restrict__ wv, const float* __restrict__ wp,
    bf16* __restrict__ Wb, bf16* __restrict__ Pb) {
  if (blockIdx.x < 512) {
    int b = blockIdx.x >> 5, g = blockIdx.x & 31;
    const float4* xp4 = (const float4*)(x + (size_t)(b * 256 + g * 8) * 1024);
    float s = 0.f, ss = 0.f;
    for (int i = threadIdx.x; i < 2048; i += 256) {
      float4 v = xp4[i];
      s  += (v.x + v.y) + (v.z + v.w);
      ss += (v.x * v.x + v.y * v.y) + (v.z * v.z + v.w * v.w);
    }
    #pragma unroll
    for (int o = 32; o; o >>= 1) { s += __shfl_down(s, o); ss += __shfl_down(ss, o); }
    __shared__ float red[2][4];
    int wid = threadIdx.x >> 6;
    if ((threadIdx.x & 63) == 0) { red[0][wid] = s; red[1][wid] = ss; }
    __syncthreads();
    if (threadIdx.x == 0) {
      s  = red[0][0] + red[0][1] + red[0][2] + red[0][3];
      ss = red[1][0] + red[1][1] + red[1][2] + red[1][3];
      float mean = s * (1.f / 8192.f);
      float var  = ss * (1.f / 8192.f) - mean * mean;
      stats[blockIdx.x] = make_float2(mean, rsqrtf(var + 1e-5f));
    }
  } else {
    int i = (blockIdx.x - 512) * 256 + threadIdx.x;   // 262144 total
    if (i < 196608) {
      int r = i >> 8, c = i & 255;
      const float* src = (r < 256) ? wq : (r < 512) ? wk : wv;
      Wb[i] = __float2bfloat16(src[(r & 255) * 256 + c]);
    } else {
      int j2 = i - 196608;                            // 0..65535
      int jj = j2 & 7, lane2 = (j2 >> 3) & 63;
      int kk2 = (j2 >> 9) & 15, w2 = j2 >> 13;
      int m = w2 * 32 + (lane2 & 31);
      int e = kk2 * 16 + (lane2 >> 5) * 8 + jj;
      Pb[j2] = __float2bfloat16(wp[m * 256 + e]);
    }
  }
}

// Fused GN + qkv GEMM. B-staging: per thread (l, 4 consecutive c) ->
// 4 coalesced f32 loads + 2 cvt_pk + one b64 LDS write.
__global__ __launch_bounds__(256) void gemm_qkv_fused(
    const float* __restrict__ x, const float* __restrict__ gamma,
    const float* __restrict__ beta, const float2* __restrict__ stats,
    const bf16* __restrict__ Wb,
    const float* __restrict__ bq, const float* __restrict__ bk,
    const float* __restrict__ bv,
    bf16* __restrict__ qkv, size_t qkv_bstride, int b_off) {
  __shared__ bf16 As[128][40];
  __shared__ bf16 Bs[128][40];
  __shared__ float2 ssh[256];
  int zb = blockIdx.z, b = zb + b_off;
  int m0 = blockIdx.y * 128, l0 = blockIdx.x * 128;
  const float* xb = x + (size_t)b * 262144;
  int tid = threadIdx.x, lane = tid & 63, wave = tid >> 6;
  int l16 = lane & 15, quad = lane >> 4;
  int mi0 = (wave & 1) * 4, nj0 = (wave >> 1) * 4;

  {
    float2 st = stats[b * 32 + (tid >> 3)];
    float sc = st.y * gamma[tid];
    ssh[tid] = make_float2(sc, beta[tid] - st.x * sc);
  }

  float4v acc[4][4];
  #pragma unroll
  for (int i = 0; i < 4; i++)
    #pragma unroll
    for (int j = 0; j < 4; j++) acc[i][j] = (float4v){0.f, 0.f, 0.f, 0.f};

  for (int kc = 0; kc < 8; kc++) {
    __syncthreads();
    #pragma unroll
    for (int it = 0; it < 2; it++) {
      int s = it * 256 + tid;
      int mm = s >> 2, kk = (s & 3) * 8;
      *(short8*)&As[mm][kk] = *(const short8*)&Wb[(size_t)(m0 + mm) * 256 + kc * 32 + kk];
    }
    // B tile: 32 c x 128 l; thread -> (ll, cg*4..cg*4+3)
    #pragma unroll
    for (int it = 0; it < 4; it++) {
      int s = it * 256 + tid;
      int ll = s & 127, cg = s >> 7;               // cg 0..7
      int c = kc * 32 + cg * 4;
      float2 sh0 = ssh[c], sh1 = ssh[c + 1], sh2 = ssh[c + 2], sh3 = ssh[c + 3];
      const float* xp = &xb[(size_t)c * 1024 + l0 + ll];
      float v0 = xp[0]    * sh0.x + sh0.y;
      float v1 = xp[1024] * sh1.x + sh1.y;
      float v2 = xp[2048] * sh2.x + sh2.y;
      float v3 = xp[3072] * sh3.x + sh3.y;
      uint2 pk;
      pk.x = cvtpk(v0, v1);
      pk.y = cvtpk(v2, v3);
      *(uint2*)&Bs[ll][cg * 4] = pk;
    }
    __syncthreads();
    short8 af[4], bfr[4];
    #pragma unroll
    for (int i = 0; i < 4; i++) af[i]  = *(const short8*)&As[(mi0 + i) * 16 + l16][quad * 8];
    #pragma unroll
    for (int j = 0; j < 4; j++) bfr[j] = *(const short8*)&Bs[(nj0 + j) * 16 + l16][quad * 8];
    #pragma unroll
    for (int i = 0; i < 4; i++)
      #pragma unroll
      for (int j = 0; j < 4; j++)
        acc[i][j] = __builtin_amdgcn_mfma_f32_16x16x32_bf16(af[i], bfr[j], acc[i][j], 0, 0, 0);
  }

  bf16* Cp = qkv + (size_t)zb * qkv_bstride;
  int sec = m0 >> 8;
  const float* bptr = (sec == 0) ? bq : (sec == 1) ? bk : bv;
  if (sec <= 1) {
    float osc = (sec == 0) ? 0.125f * 1.4426950408889634f : 1.0f;
    bf16* Tp = Cp + sec * 262144;
    #pragma unroll
    for (int i = 0; i < 4; i++) {
      int rrb = (m0 & 255) + (mi0 + i) * 16 + quad * 4;
      int nh = rrb >> 6, d0 = rrb & 63;
      float b0 = bptr[rrb], b1 = bptr[rrb + 1], b2 = bptr[rrb + 2], b3 = bptr[rrb + 3];
      bf16* Tph = Tp + nh * 65536;
      #pragma unroll
      for (int j = 0; j < 4; j++) {
        int l = l0 + (nj0 + j) * 16 + l16;
        uint2 pk;
        pk.x = cvtpk((acc[i][j][0] + b0) * osc, (acc[i][j][1] + b1) * osc);
        pk.y = cvtpk((acc[i][j][2] + b2) * osc, (acc[i][j][3] + b3) * osc);
        *(uint2*)&Tph[qk_fidx(d0, l)] = pk;
      }
    }
  } else {
    bf16* Vfp = Cp + 524288;
    #pragma unroll
    for (int i = 0; i < 4; i++)
      #pragma unroll
      for (int rp = 0; rp < 2; rp++) {
        int rr = (m0 & 255) + (mi0 + i) * 16 + quad * 4 + rp * 2;
        int nh = rr >> 6, d = rr & 63;
        float b0 = bptr[rr], b1 = bptr[rr + 1];
        bf16* Vfh = Vfp + nh * 65536;
        #pragma unroll
        for (int j = 0; j < 4; j++) {
          int l = l0 + (nj0 + j) * 16 + l16;
          unsigned int pk = cvtpk(acc[i][j][rp * 2] + b0, acc[i][j][rp * 2 + 1] + b1);
          *(unsigned short*)&Vfh[v_fidx(d, l)] = (unsigned short)pk;
          *(unsigned short*)&Vfh[v_fidx(d + 1, l)] = (unsigned short)(pk >> 16);
        }
      }
  }
}

// Fused flash attention + output projection + residual (structure = R25).
__global__ __launch_bounds__(512) void attn_proj_kernel(
    const bf16* __restrict__ qkv, const bf16* __restrict__ PbF,
    const float* __restrict__ bproj, const float* __restrict__ x,
    float* __restrict__ out, size_t qkv_bstride, int b_off) {
  __shared__ __align__(16) char lds[52736];
  float* OB   = (float*)lds;              // [4 heads][32 q][68] f32 = 34816 B
  float* mL   = (float*)(lds + 34816);    // [4][32]
  float* lL   = (float*)(lds + 35328);    // [4][32]
  bf16*  O_lds = (bf16*)(lds + 35840);    // [32 q][264 e] = 16896 B

  int b, qg;
  {
    int f = blockIdx.x;
    if (gridDim.x == 512) {               // XCD swizzle: wgid%8 == b%8
      int c = f & 7, t = f >> 3;
      b = ((t & 1) << 3) + c; qg = t >> 1;
    } else {
      b = b_off; qg = f;
    }
  }
  const bf16* base = qkv + (size_t)(gridDim.x == 512 ? b : 0) * qkv_bstride;
  int tid = threadIdx.x;
  int lane = tid & 63, wave = tid >> 6;
  int l31 = lane & 31, hb2 = lane >> 5;
  int n = wave & 3, half = wave >> 2;
  const bf16* Qf = base + n * 65536;
  const bf16* Kf = base + 262144 + n * 65536;
  const bf16* Vf = base + 524288 + n * 65536;

  short8 qb[4];
  #pragma unroll
  for (int ds = 0; ds < 4; ds++)
    qb[ds] = *(const short8*)&Qf[(((qg * 4 + ds) << 6) + lane) << 3];

  float m_run = -1e30f, l_run = 0.f;
  float16v oaccT[2];
  #pragma unroll
  for (int dh = 0; dh < 2; dh++)
    #pragma unroll
    for (int r = 0; r < 16; r++) oaccT[dh][r] = 0.f;

  auto swp = [&](unsigned int a, unsigned int bb, unsigned int& o0, unsigned int& o1) {
#if __has_builtin(__builtin_amdgcn_permlane32_swap)
    auto rr = __builtin_amdgcn_permlane32_swap((int)a, (int)bb, false, false);
    o0 = (unsigned int)rr[0]; o1 = (unsigned int)rr[1];
#else
    unsigned int sa = (unsigned int)__shfl_xor((int)a, 32, 64);
    unsigned int sb = (unsigned int)__shfl_xor((int)bb, 32, 64);
    o0 = hb2 ? sb : a;
    o1 = hb2 ? bb : sa;
#endif
  };

  int k0 = half << 4;
  for (int kt = k0; kt < k0 + 16; kt++) {
    short8 kf[4];
    #pragma unroll
    for (int ds = 0; ds < 4; ds++)
      kf[ds] = *(const short8*)&Kf[(((kt * 4 + ds) << 6) + lane) << 3];
    short8 vf[2][2];
    #pragma unroll
    for (int dh = 0; dh < 2; dh++)
      #pragma unroll
      for (int s = 0; s < 2; s++)
        vf[dh][s] = *(const short8*)&Vf[((((kt * 2 + dh) * 2 + s) << 6) + lane) << 3];

    float16v sacc;
    #pragma unroll
    for (int r = 0; r < 16; r++) sacc[r] = 0.f;
    #pragma unroll
    for (int ds = 0; ds < 4; ds++)
      sacc = __builtin_amdgcn_mfma_f32_32x32x16_bf16(kf[ds], qb[ds], sacc, 0, 0, 0);

    float a0 = max3f(sacc[0], sacc[1], sacc[2]);
    float a1 = max3f(sacc[3], sacc[4], sacc[5]);
    float a2 = max3f(sacc[6], sacc[7], sacc[8]);
    float a3 = max3f(sacc[9], sacc[10], sacc[11]);
    float a4 = max3f(sacc[12], sacc[13], sacc[14]);
    float cmax = fmaxf(max3f(a0, a1, a2), max3f(a3, a4, sacc[15]));
    cmax = fmaxf(cmax, __shfl_xor(cmax, 32, 64));

    if (__any(cmax > m_run + 8.f)) {
      float mnew = fmaxf(m_run, cmax);
      float alpha = EXP2F(m_run - mnew);
      #pragma unroll
      for (int dh = 0; dh < 2; dh++)
        #pragma unroll
        for (int r = 0; r < 16; r++) oaccT[dh][r] *= alpha;
      l_run *= alpha;
      m_run = mnew;
    }

    float p[16];
    #pragma unroll
    for (int r = 0; r < 16; r++) p[r] = EXP2F(sacc[r] - m_run);
    float s0 = (p[0] + p[1]) + (p[2] + p[3]);
    float s1 = (p[4] + p[5]) + (p[6] + p[7]);
    float s2 = (p[8] + p[9]) + (p[10] + p[11]);
    float s3 = (p[12] + p[13]) + (p[14] + p[15]);
    float psum = (s0 + s1) + (s2 + s3);
    psum += __shfl_xor(psum, 32, 64);
    l_run += psum;

    unsigned int w[8];
    #pragma unroll
    for (int i = 0; i < 8; i++) w[i] = cvtpk(p[2 * i], p[2 * i + 1]);
    short8 pb[2];
    {
      unsigned int o0, o1, o2, o3;
      swp(w[0], w[2], o0, o2); swp(w[1], w[3], o1, o3);
      unsigned int* pw = (unsigned int*)&pb[0];
      pw[0] = o0; pw[1] = o1; pw[2] = o2; pw[3] = o3;
      swp(w[4], w[6], o0, o2); swp(w[5], w[7], o1, o3);
      pw = (unsigned int*)&pb[1];
      pw[0] = o0; pw[1] = o1; pw[2] = o2; pw[3] = o3;
    }

    #pragma unroll
    for (int dh = 0; dh < 2; dh++)
      #pragma unroll
      for (int s = 0; s < 2; s++)
        oaccT[dh] = __builtin_amdgcn_mfma_f32_32x32x16_bf16(vf[dh][s], pb[s], oaccT[dh], 0, 0, 0);
  }

  // half-1 waves dump partials; half-0 waves merge -> O_lds (bf16)
  if (half == 1) {
    float* OBn = OB + n * 2176;
    #pragma unroll
    for (int dh = 0; dh < 2; dh++)
      #pragma unroll
      for (int rq = 0; rq < 4; rq++) {
        float4v t = {oaccT[dh][4 * rq], oaccT[dh][4 * rq + 1],
                     oaccT[dh][4 * rq + 2], oaccT[dh][4 * rq + 3]};
        *(float4v*)&OBn[l31 * 68 + dh * 32 + 8 * rq + 4 * hb2] = t;
      }
    if (hb2 == 0) { mL[n * 32 + l31] = m_run; lL[n * 32 + l31] = l_run; }
  }
  __syncthreads();
  if (half == 0) {
    float mB = mL[n * 32 + l31], lB = lL[n * 32 + l31];
    float ms = fmaxf(m_run, mB);
    float eA = EXP2F(m_run - ms), eB = EXP2F(mB - ms);
    float inv = 1.f / (l_run * eA + lB * eB);
    eA *= inv; eB *= inv;
    const float* OBn = OB + n * 2176 + l31 * 68;
    bf16* orow = O_lds + l31 * 264 + n * 64;
    #pragma unroll
    for (int dh = 0; dh < 2; dh++)
      #pragma unroll
      for (int rp = 0; rp < 8; rp++) {
        int r = rp * 2;
        int d = dh * 32 + (r & 3) + 8 * (r >> 2) + 4 * hb2;
        unsigned int pk = cvtpk(oaccT[dh][r] * eA + OBn[d] * eB,
                                oaccT[dh][r + 1] * eA + OBn[d + 1] * eB);
        *(unsigned int*)&orow[d] = pk;
      }
  }
  __syncthreads();

  // proj: wave w -> out rows m = 32w .. 32w+31 for l = qg*32 .. +31
  float16v pacc;
  #pragma unroll
  for (int r = 0; r < 16; r++) pacc[r] = 0.f;
  #pragma unroll
  for (int kk = 0; kk < 16; kk++) {
    short8 a = *(const short8*)&O_lds[l31 * 264 + kk * 16 + hb2 * 8];
    short8 bb = *(const short8*)&PbF[(((wave * 16 + kk) << 6) + lane) << 3];
    pacc = __builtin_amdgcn_mfma_f32_32x32x16_bf16(a, bb, pacc, 0, 0, 0);
  }
  int m = (wave << 5) + l31;
  float bias = bproj[m];
  const float* xr = x + (((size_t)(b * 256 + m)) << 10) + (qg << 5);
  float* orw = out + (((size_t)(b * 256 + m)) << 10) + (qg << 5);
  #pragma unroll
  for (int rp = 0; rp < 8; rp++) {
    int r = rp * 2;
    int ll = (r & 3) + 8 * (r >> 2) + 4 * hb2;
    float2 xv = *(const float2*)&xr[ll];
    float2 ov;
    ov.x = pacc[r] + bias + xv.x;
    ov.y = pacc[r + 1] + bias + xv.y;
    *(float2*)&orw[ll] = ov;
  }
}

extern "C" void kernel_launch(void* const* d_in, const int* in_sizes, int n_in,
                              void* d_out, int out_size, void* d_ws, size_t ws_size,
                              hipStream_t stream) {
  int ix = 0, iga = 1, ibe = 2, iwq = 3, ibq = 4, iwk = 5, ibk = 6,
      iwv = 7, ibv = 8, iwp = 9, ibp = 10;
  if (in_sizes[0] != 4194304) {
    if (in_sizes[10] == 4194304 && in_sizes[1] == 256) {
      ibe = 0; ibk = 1; ibp = 2; ibq = 3; ibv = 4; iga = 5;
      iwk = 6; iwp = 7; iwq = 8; iwv = 9; ix = 10;
    } else if (in_sizes[10] == 4194304 && in_sizes[1] == 65536) {
      ibp = 0; iwp = 1; ibv = 2; iwv = 3; ibk = 4; iwk = 5;
      ibq = 6; iwq = 7; ibe = 8; iga = 9; ix = 10;
    } else {
      for (int i = 0; i < 11; i++) if (in_sizes[i] == 4194304) ix = i;
    }
  }
  const float* x     = (const float*)d_in[ix];
  const float* gamma = (const float*)d_in[iga];
  const float* beta  = (const float*)d_in[ibe];
  const float* wq    = (const float*)d_in[iwq];
  const float* bq    = (const float*)d_in[ibq];
  const float* wk    = (const float*)d_in[iwk];
  const float* bk    = (const float*)d_in[ibk];
  const float* wv    = (const float*)d_in[iwv];
  const float* bv    = (const float*)d_in[ibv];
  const float* wproj = (const float*)d_in[iwp];
  const float* bproj = (const float*)d_in[ibp];
  float* out = (float*)d_out;

  const size_t QKV_B = (size_t)768 * 1024;   // elements per batch
  char* wsp = (char*)d_ws;
  float2* stats = (float2*)wsp;                        // 4 KB
  bf16* Wb = (bf16*)(wsp + 8192);                      // 384 KB
  bf16* Pb = (bf16*)(wsp + 8192 + 393216);             // 128 KB (frag-major)
  const size_t QKV0 = 8192 + 393216 + 131072;
  size_t full_need = QKV0 + (size_t)16 * QKV_B * 2;    // ~24.7 MB

  stats_wpack_kernel<<<1536, 256, 0, stream>>>(x, stats, wq, wk, wv, wproj, Wb, Pb);

  if (ws_size >= full_need) {
    bf16* qkv = (bf16*)(wsp + QKV0);                   // 24 MB
    gemm_qkv_fused<<<dim3(8, 6, 16), 256, 0, stream>>>(x, gamma, beta, stats, Wb,
                                                       bq, bk, bv, qkv, QKV_B, 0);
    attn_proj_kernel<<<512, 512, 0, stream>>>(qkv, Pb, bproj, x, out, QKV_B, 0);
  } else {
    bf16* qkv = (bf16*)(wsp + QKV0);
    for (int b = 0; b < 16; b++) {
      gemm_qkv_fused<<<dim3(8, 6, 1), 256, 0, stream>>>(x, gamma, beta, stats, Wb,
                                                        bq, bk, bv, qkv, 0, b);
      attn_proj_kernel<<<32, 512, 0, stream>>>(qkv, Pb, bproj, x, out, 0, b);
    }
  }
}

// Round 11
// 144.375 us; speedup vs baseline: 1.5073x; 1.0191x over previous
//
#include <hip/hip_runtime.h>
#include <hip/hip_bf16.h>
#include <stdint.h>

// Problem constants (B=16, C=256, NH=4, D=64, G=32, L=HW=1024)
// Round 27. R26 = 147.1us; all kernels < 43us (below harness fills).
// attn_proj arithmetic says issue-bound floor ~11us but runtime ~40us ->
// load-latency on the serial K->S-MFMA chain. Two causes fixed here:
//  1) XCD producer/consumer matching: gemm_qkv grid flattened to 768
//     blocks, swizzled so ALL blocks of batch b run on XCD b%8 - the same
//     XCD attn_proj reads batch b from (its swizzle is wgid%8==b%8).
//     qkv writes stay in that XCD's L2 (1.5MB/batch, 2 batches/XCD);
//     attn K/V loads become local-L2 hits instead of cross-XCD misses.
//     Also gives gemm's 6x x re-reads single-XCD locality.
//  2) 1-ahead K prefetch in attn_proj kt loop (R19 double-buffer pattern,
//     +32 VGPR, stays ~<=128 so 4 waves/SIMD holds). V already issued
//     early / consumed late within a step.
// Kernel bodies otherwise unchanged from R26 (green, absmax 0.03125).

typedef __hip_bfloat16 bf16;
typedef __attribute__((ext_vector_type(8))) short short8;
typedef __attribute__((ext_vector_type(4))) float float4v;
typedef __attribute__((ext_vector_type(16))) float float16v;

#if __has_builtin(__builtin_amdgcn_exp2f)
#define EXP2F(x) __builtin_amdgcn_exp2f(x)
#else
#define EXP2F(x) exp2f(x)
#endif

__device__ __forceinline__ float max3f(float a, float b, float c) {
  return fmaxf(fmaxf(a, b), c);
}
__device__ __forceinline__ unsigned int cvtpk(float lo, float hi) {
  unsigned int pk;
  asm("v_cvt_pk_bf16_f32 %0, %1, %2" : "=v"(pk) : "v"(lo), "v"(hi));
  return pk;
}

// fragment-major index for Q^T/K^T per head: element (d, l) of Q[d][l]
__device__ __forceinline__ int qk_fidx(int d, int l) {
  return ((((l >> 5) * 4 + (d >> 4)) * 64 + ((d >> 3) & 1) * 32 + (l & 31)) << 3) + (d & 7);
}
// fragment-major index for V per head: element (d, l) of V[d][l]
__device__ __forceinline__ int v_fidx(int d, int l) {
  return (((((((l >> 5) * 2 + (d >> 5)) * 2 + ((l >> 4) & 1)) * 2 + ((l >> 3) & 1)) * 32) + (d & 31)) << 3) + (l & 7);
}

// stats (512 blocks) + weight pack (1024 blocks) in one launch.
__global__ __launch_bounds__(256) void stats_wpack_kernel(
    const float* __restrict__ x, float2* __restrict__ stats,
    const float* __restrict__ wq, const float* __restrict__ wk,
    const float* __restrict__ wv, const float* __restrict__ wp,
    bf16* __restrict__ Wb, bf16* __restrict__ Pb) {
  if (blockIdx.x < 512) {
    int b = blockIdx.x >> 5, g = blockIdx.x & 31;
    const float4* xp4 = (const float4*)(x + (size_t)(b * 256 + g * 8) * 1024);
    float s = 0.f, ss = 0.f;
    for (int i = threadIdx.x; i < 2048; i += 256) {
      float4 v = xp4[i];
      s  += (v.x + v.y) + (v.z + v.w);
      ss += (v.x * v.x + v.y * v.y) + (v.z * v.z + v.w * v.w);
    }
    #pragma unroll
    for (int o = 32; o; o >>= 1) { s += __shfl_down(s, o); ss += __shfl_down(ss, o); }
    __shared__ float red[2][4];
    int wid = threadIdx.x >> 6;
    if ((threadIdx.x & 63) == 0) { red[0][wid] = s; red[1][wid] = ss; }
    __syncthreads();
    if (threadIdx.x == 0) {
      s  = red[0][0] + red[0][1] + red[0][2] + red[0][3];
      ss = red[1][0] + red[1][1] + red[1][2] + red[1][3];
      float mean = s * (1.f / 8192.f);
      float var  = ss * (1.f / 8192.f) - mean * mean;
      stats[blockIdx.x] = make_float2(mean, rsqrtf(var + 1e-5f));
    }
  } else {
    int i = (blockIdx.x - 512) * 256 + threadIdx.x;   // 262144 total
    if (i < 196608) {
      int r = i >> 8, c = i & 255;
      const float* src = (r < 256) ? wq : (r < 512) ? wk : wv;
      Wb[i] = __float2bfloat16(src[(r & 255) * 256 + c]);
    } else {
      int j2 = i - 196608;                            // 0..65535
      int jj = j2 & 7, lane2 = (j2 >> 3) & 63;
      int kk2 = (j2 >> 9) & 15, w2 = j2 >> 13;
      int m = w2 * 32 + (lane2 & 31);
      int e = kk2 * 16 + (lane2 >> 5) * 8 + jj;
      Pb[j2] = __float2bfloat16(wp[m * 256 + e]);
    }
  }
}

// Fused GN + qkv GEMM. Full path: flat 768-block grid, XCD-swizzled so all
// 48 blocks of batch b run on XCD b%8 (matches attn_proj's reader swizzle).
__global__ __launch_bounds__(256) void gemm_qkv_fused(
    const float* __restrict__ x, const float* __restrict__ gamma,
    const float* __restrict__ beta, const float2* __restrict__ stats,
    const bf16* __restrict__ Wb,
    const float* __restrict__ bq, const float* __restrict__ bk,
    const float* __restrict__ bv,
    bf16* __restrict__ qkv, size_t qkv_bstride, int b_off) {
  __shared__ bf16 As[128][40];
  __shared__ bf16 Bs[128][40];
  __shared__ float2 ssh[256];
  int zb, m0, l0;
  if (gridDim.x == 768) {
    int f = blockIdx.x;
    int c = f & 7, t = f >> 3;
    zb = (t & 1) * 8 + c;                 // wgid%8 == zb%8 -> XCD match
    int rem = t >> 1;                     // 0..47
    m0 = (rem % 6) * 128;
    l0 = (rem / 6) * 128;
  } else {
    zb = blockIdx.z; m0 = blockIdx.y * 128; l0 = blockIdx.x * 128;
  }
  int b = zb + b_off;
  const float* xb = x + (size_t)b * 262144;
  int tid = threadIdx.x, lane = tid & 63, wave = tid >> 6;
  int l16 = lane & 15, quad = lane >> 4;
  int mi0 = (wave & 1) * 4, nj0 = (wave >> 1) * 4;

  {
    float2 st = stats[b * 32 + (tid >> 3)];
    float sc = st.y * gamma[tid];
    ssh[tid] = make_float2(sc, beta[tid] - st.x * sc);
  }

  float4v acc[4][4];
  #pragma unroll
  for (int i = 0; i < 4; i++)
    #pragma unroll
    for (int j = 0; j < 4; j++) acc[i][j] = (float4v){0.f, 0.f, 0.f, 0.f};

  for (int kc = 0; kc < 8; kc++) {
    __syncthreads();
    #pragma unroll
    for (int it = 0; it < 2; it++) {
      int s = it * 256 + tid;
      int mm = s >> 2, kk = (s & 3) * 8;
      *(short8*)&As[mm][kk] = *(const short8*)&Wb[(size_t)(m0 + mm) * 256 + kc * 32 + kk];
    }
    // B tile: 32 c x 128 l; thread -> (ll, cg*4..cg*4+3)
    #pragma unroll
    for (int it = 0; it < 4; it++) {
      int s = it * 256 + tid;
      int ll = s & 127, cg = s >> 7;               // cg 0..7
      int c = kc * 32 + cg * 4;
      float2 sh0 = ssh[c], sh1 = ssh[c + 1], sh2 = ssh[c + 2], sh3 = ssh[c + 3];
      const float* xp = &xb[(size_t)c * 1024 + l0 + ll];
      float v0 = xp[0]    * sh0.x + sh0.y;
      float v1 = xp[1024] * sh1.x + sh1.y;
      float v2 = xp[2048] * sh2.x + sh2.y;
      float v3 = xp[3072] * sh3.x + sh3.y;
      uint2 pk;
      pk.x = cvtpk(v0, v1);
      pk.y = cvtpk(v2, v3);
      *(uint2*)&Bs[ll][cg * 4] = pk;
    }
    __syncthreads();
    short8 af[4], bfr[4];
    #pragma unroll
    for (int i = 0; i < 4; i++) af[i]  = *(const short8*)&As[(mi0 + i) * 16 + l16][quad * 8];
    #pragma unroll
    for (int j = 0; j < 4; j++) bfr[j] = *(const short8*)&Bs[(nj0 + j) * 16 + l16][quad * 8];
    #pragma unroll
    for (int i = 0; i < 4; i++)
      #pragma unroll
      for (int j = 0; j < 4; j++)
        acc[i][j] = __builtin_amdgcn_mfma_f32_16x16x32_bf16(af[i], bfr[j], acc[i][j], 0, 0, 0);
  }

  bf16* Cp = qkv + (size_t)zb * qkv_bstride;
  int sec = m0 >> 8;
  const float* bptr = (sec == 0) ? bq : (sec == 1) ? bk : bv;
  if (sec <= 1) {
    float osc = (sec == 0) ? 0.125f * 1.4426950408889634f : 1.0f;
    bf16* Tp = Cp + sec * 262144;
    #pragma unroll
    for (int i = 0; i < 4; i++) {
      int rrb = (m0 & 255) + (mi0 + i) * 16 + quad * 4;
      int nh = rrb >> 6, d0 = rrb & 63;
      float b0 = bptr[rrb], b1 = bptr[rrb + 1], b2 = bptr[rrb + 2], b3 = bptr[rrb + 3];
      bf16* Tph = Tp + nh * 65536;
      #pragma unroll
      for (int j = 0; j < 4; j++) {
        int l = l0 + (nj0 + j) * 16 + l16;
        uint2 pk;
        pk.x = cvtpk((acc[i][j][0] + b0) * osc, (acc[i][j][1] + b1) * osc);
        pk.y = cvtpk((acc[i][j][2] + b2) * osc, (acc[i][j][3] + b3) * osc);
        *(uint2*)&Tph[qk_fidx(d0, l)] = pk;
      }
    }
  } else {
    bf16* Vfp = Cp + 524288;
    #pragma unroll
    for (int i = 0; i < 4; i++)
      #pragma unroll
      for (int rp = 0; rp < 2; rp++) {
        int rr = (m0 & 255) + (mi0 + i) * 16 + quad * 4 + rp * 2;
        int nh = rr >> 6, d = rr & 63;
        float b0 = bptr[rr], b1 = bptr[rr + 1];
        bf16* Vfh = Vfp + nh * 65536;
        #pragma unroll
        for (int j = 0; j < 4; j++) {
          int l = l0 + (nj0 + j) * 16 + l16;
          unsigned int pk = cvtpk(acc[i][j][rp * 2] + b0, acc[i][j][rp * 2 + 1] + b1);
          *(unsigned short*)&Vfh[v_fidx(d, l)] = (unsigned short)pk;
          *(unsigned short*)&Vfh[v_fidx(d + 1, l)] = (unsigned short)(pk >> 16);
        }
      }
  }
}

// Fused flash attention + output projection + residual (structure = R26)
// + 1-ahead K prefetch in the kt loop.
__global__ __launch_bounds__(512) void attn_proj_kernel(
    const bf16* __restrict__ qkv, const bf16* __restrict__ PbF,
    const float* __restrict__ bproj, const float* __restrict__ x,
    float* __restrict__ out, size_t qkv_bstride, int b_off) {
  __shared__ __align__(16) char lds[52736];
  float* OB   = (float*)lds;              // [4 heads][32 q][68] f32 = 34816 B
  float* mL   = (float*)(lds + 34816);    // [4][32]
  float* lL   = (float*)(lds + 35328);    // [4][32]
  bf16*  O_lds = (bf16*)(lds + 35840);    // [32 q][264 e] = 16896 B

  int b, qg;
  {
    int f = blockIdx.x;
    if (gridDim.x == 512) {               // XCD swizzle: wgid%8 == b%8
      int c = f & 7, t = f >> 3;
      b = ((t & 1) << 3) + c; qg = t >> 1;
    } else {
      b = b_off; qg = f;
    }
  }
  const bf16* base = qkv + (size_t)(gridDim.x == 512 ? b : 0) * qkv_bstride;
  int tid = threadIdx.x;
  int lane = tid & 63, wave = tid >> 6;
  int l31 = lane & 31, hb2 = lane >> 5;
  int n = wave & 3, half = wave >> 2;
  const bf16* Qf = base + n * 65536;
  const bf16* Kf = base + 262144 + n * 65536;
  const bf16* Vf = base + 524288 + n * 65536;

  short8 qb[4];
  #pragma unroll
  for (int ds = 0; ds < 4; ds++)
    qb[ds] = *(const short8*)&Qf[(((qg * 4 + ds) << 6) + lane) << 3];

  float m_run = -1e30f, l_run = 0.f;
  float16v oaccT[2];
  #pragma unroll
  for (int dh = 0; dh < 2; dh++)
    #pragma unroll
    for (int r = 0; r < 16; r++) oaccT[dh][r] = 0.f;

  auto swp = [&](unsigned int a, unsigned int bb, unsigned int& o0, unsigned int& o1) {
#if __has_builtin(__builtin_amdgcn_permlane32_swap)
    auto rr = __builtin_amdgcn_permlane32_swap((int)a, (int)bb, false, false);
    o0 = (unsigned int)rr[0]; o1 = (unsigned int)rr[1];
#else
    unsigned int sa = (unsigned int)__shfl_xor((int)a, 32, 64);
    unsigned int sb = (unsigned int)__shfl_xor((int)bb, 32, 64);
    o0 = hb2 ? sb : a;
    o1 = hb2 ? bb : sa;
#endif
  };

  auto loadK = [&](short8 (&kf)[4], int kt) {
    #pragma unroll
    for (int ds = 0; ds < 4; ds++)
      kf[ds] = *(const short8*)&Kf[(((kt * 4 + ds) << 6) + lane) << 3];
  };

  auto step = [&](short8 (&kf)[4], int kt) {
    short8 vf[2][2];
    #pragma unroll
    for (int dh = 0; dh < 2; dh++)
      #pragma unroll
      for (int s = 0; s < 2; s++)
        vf[dh][s] = *(const short8*)&Vf[((((kt * 2 + dh) * 2 + s) << 6) + lane) << 3];

    float16v sacc;
    #pragma unroll
    for (int r = 0; r < 16; r++) sacc[r] = 0.f;
    #pragma unroll
    for (int ds = 0; ds < 4; ds++)
      sacc = __builtin_amdgcn_mfma_f32_32x32x16_bf16(kf[ds], qb[ds], sacc, 0, 0, 0);

    float a0 = max3f(sacc[0], sacc[1], sacc[2]);
    float a1 = max3f(sacc[3], sacc[4], sacc[5]);
    float a2 = max3f(sacc[6], sacc[7], sacc[8]);
    float a3 = max3f(sacc[9], sacc[10], sacc[11]);
    float a4 = max3f(sacc[12], sacc[13], sacc[14]);
    float cmax = fmaxf(max3f(a0, a1, a2), max3f(a3, a4, sacc[15]));
    cmax = fmaxf(cmax, __shfl_xor(cmax, 32, 64));

    if (__any(cmax > m_run + 8.f)) {
      float mnew = fmaxf(m_run, cmax);
      float alpha = EXP2F(m_run - mnew);
      #pragma unroll
      for (int dh = 0; dh < 2; dh++)
        #pragma unroll
        for (int r = 0; r < 16; r++) oaccT[dh][r] *= alpha;
      l_run *= alpha;
      m_run = mnew;
    }

    float p[16];
    #pragma unroll
    for (int r = 0; r < 16; r++) p[r] = EXP2F(sacc[r] - m_run);
    float s0 = (p[0] + p[1]) + (p[2] + p[3]);
    float s1 = (p[4] + p[5]) + (p[6] + p[7]);
    float s2 = (p[8] + p[9]) + (p[10] + p[11]);
    float s3 = (p[12] + p[13]) + (p[14] + p[15]);
    float psum = (s0 + s1) + (s2 + s3);
    psum += __shfl_xor(psum, 32, 64);
    l_run += psum;

    unsigned int w[8];
    #pragma unroll
    for (int i = 0; i < 8; i++) w[i] = cvtpk(p[2 * i], p[2 * i + 1]);
    short8 pb[2];
    {
      unsigned int o0, o1, o2, o3;
      swp(w[0], w[2], o0, o2); swp(w[1], w[3], o1, o3);
      unsigned int* pw = (unsigned int*)&pb[0];
      pw[0] = o0; pw[1] = o1; pw[2] = o2; pw[3] = o3;
      swp(w[4], w[6], o0, o2); swp(w[5], w[7], o1, o3);
      pw = (unsigned int*)&pb[1];
      pw[0] = o0; pw[1] = o1; pw[2] = o2; pw[3] = o3;
    }

    #pragma unroll
    for (int dh = 0; dh < 2; dh++)
      #pragma unroll
      for (int s = 0; s < 2; s++)
        oaccT[dh] = __builtin_amdgcn_mfma_f32_32x32x16_bf16(vf[dh][s], pb[s], oaccT[dh], 0, 0, 0);
  };

  // kt loop with 1-ahead K prefetch (register double-buffer)
  int k0 = half << 4;
  short8 kfA[4], kfB[4];
  loadK(kfA, k0);
  #pragma unroll
  for (int i = 0; i < 8; i++) {
    loadK(kfB, k0 + 2 * i + 1);
    step(kfA, k0 + 2 * i);
    if (i < 7) loadK(kfA, k0 + 2 * i + 2);
    step(kfB, k0 + 2 * i + 1);
  }

  // half-1 waves dump partials; half-0 waves merge -> O_lds (bf16)
  if (half == 1) {
    float* OBn = OB + n * 2176;
    #pragma unroll
    for (int dh = 0; dh < 2; dh++)
      #pragma unroll
      for (int rq = 0; rq < 4; rq++) {
        float4v t = {oaccT[dh][4 * rq], oaccT[dh][4 * rq + 1],
                     oaccT[dh][4 * rq + 2], oaccT[dh][4 * rq + 3]};
        *(float4v*)&OBn[l31 * 68 + dh * 32 + 8 * rq + 4 * hb2] = t;
      }
    if (hb2 == 0) { mL[n * 32 + l31] = m_run; lL[n * 32 + l31] = l_run; }
  }
  __syncthreads();
  if (half == 0) {
    float mB = mL[n * 32 + l31], lB = lL[n * 32 + l31];
    float ms = fmaxf(m_run, mB);
    float eA = EXP2F(m_run - ms), eB = EXP2F(mB - ms);
    float inv = 1.f / (l_run * eA + lB * eB);
    eA *= inv; eB *= inv;
    const float* OBn = OB + n * 2176 + l31 * 68;
    bf16* orow = O_lds + l31 * 264 + n * 64;
    #pragma unroll
    for (int dh = 0; dh < 2; dh++)
      #pragma unroll
      for (int rp = 0; rp < 8; rp++) {
        int r = rp * 2;
        int d = dh * 32 + (r & 3) + 8 * (r >> 2) + 4 * hb2;
        unsigned int pk = cvtpk(oaccT[dh][r] * eA + OBn[d] * eB,
                                oaccT[dh][r + 1] * eA + OBn[d + 1] * eB);
        *(unsigned int*)&orow[d] = pk;
      }
  }
  __syncthreads();

  // proj: wave w -> out rows m = 32w .. 32w+31 for l = qg*32 .. +31
  float16v pacc;
  #pragma unroll
  for (int r = 0; r < 16; r++) pacc[r] = 0.f;
  #pragma unroll
  for (int kk = 0; kk < 16; kk++) {
    short8 a = *(const short8*)&O_lds[l31 * 264 + kk * 16 + hb2 * 8];
    short8 bb = *(const short8*)&PbF[(((wave * 16 + kk) << 6) + lane) << 3];
    pacc = __builtin_amdgcn_mfma_f32_32x32x16_bf16(a, bb, pacc, 0, 0, 0);
  }
  int m = (wave << 5) + l31;
  float bias = bproj[m];
  const float* xr = x + (((size_t)(b * 256 + m)) << 10) + (qg << 5);
  float* orw = out + (((size_t)(b * 256 + m)) << 10) + (qg << 5);
  #pragma unroll
  for (int rp = 0; rp < 8; rp++) {
    int r = rp * 2;
    int ll = (r & 3) + 8 * (r >> 2) + 4 * hb2;
    float2 xv = *(const float2*)&xr[ll];
    float2 ov;
    ov.x = pacc[r] + bias + xv.x;
    ov.y = pacc[r + 1] + bias + xv.y;
    *(float2*)&orw[ll] = ov;
  }
}

extern "C" void kernel_launch(void* const* d_in, const int* in_sizes, int n_in,
                              void* d_out, int out_size, void* d_ws, size_t ws_size,
                              hipStream_t stream) {
  int ix = 0, iga = 1, ibe = 2, iwq = 3, ibq = 4, iwk = 5, ibk = 6,
      iwv = 7, ibv = 8, iwp = 9, ibp = 10;
  if (in_sizes[0] != 4194304) {
    if (in_sizes[10] == 4194304 && in_sizes[1] == 256) {
      ibe = 0; ibk = 1; ibp = 2; ibq = 3; ibv = 4; iga = 5;
      iwk = 6; iwp = 7; iwq = 8; iwv = 9; ix = 10;
    } else if (in_sizes[10] == 4194304 && in_sizes[1] == 65536) {
      ibp = 0; iwp = 1; ibv = 2; iwv = 3; ibk = 4; iwk = 5;
      ibq = 6; iwq = 7; ibe = 8; iga = 9; ix = 10;
    } else {
      for (int i = 0; i < 11; i++) if (in_sizes[i] == 4194304) ix = i;
    }
  }
  const float* x     = (const float*)d_in[ix];
  const float* gamma = (const float*)d_in[iga];
  const float* beta  = (const float*)d_in[ibe];
  const float* wq    = (const float*)d_in[iwq];
  const float* bq    = (const float*)d_in[ibq];
  const float* wk    = (const float*)d_in[iwk];
  const float* bk    = (const float*)d_in[ibk];
  const float* wv    = (const float*)d_in[iwv];
  const float* bv    = (const float*)d_in[ibv];
  const float* wproj = (const float*)d_in[iwp];
  const float* bproj = (const float*)d_in[ibp];
  float* out = (float*)d_out;

  const size_t QKV_B = (size_t)768 * 1024;   // elements per batch
  char* wsp = (char*)d_ws;
  float2* stats = (float2*)wsp;                        // 4 KB
  bf16* Wb = (bf16*)(wsp + 8192);                      // 384 KB
  bf16* Pb = (bf16*)(wsp + 8192 + 393216);             // 128 KB (frag-major)
  const size_t QKV0 = 8192 + 393216 + 131072;
  size_t full_need = QKV0 + (size_t)16 * QKV_B * 2;    // ~24.7 MB

  stats_wpack_kernel<<<1536, 256, 0, stream>>>(x, stats, wq, wk, wv, wproj, Wb, Pb);

  if (ws_size >= full_need) {
    bf16* qkv = (bf16*)(wsp + QKV0);                   // 24 MB
    gemm_qkv_fused<<<768, 256, 0, stream>>>(x, gamma, beta, stats, Wb,
                                            bq, bk, bv, qkv, QKV_B, 0);
    attn_proj_kernel<<<512, 512, 0, stream>>>(qkv, Pb, bproj, x, out, QKV_B, 0);
  } else {
    bf16* qkv = (bf16*)(wsp + QKV0);
    for (int b = 0; b < 16; b++) {
      gemm_qkv_fused<<<dim3(8, 6, 1), 256, 0, stream>>>(x, gamma, beta, stats, Wb,
                                                        bq, bk, bv, qkv, 0, b);
      attn_proj_kernel<<<32, 512, 0, stream>>>(qkv, Pb, bproj, x, out, 0, b);
    }
  }
}